// Round 8
// baseline (152.378 us; speedup 1.0000x reference)
//
#include <hip/hip_runtime.h>
#include <hip/hip_bf16.h>
#include <cstdint>

// Problem constants (from reference)
#define B_SZ   2
#define L_SEQ  2048
#define HID    4096
#define NH     16
#define NKV    4
#define HD     64
#define NQKV   (NH + 2*NKV)      // 24
#define QKV_N  (NQKV*HD)         // 1536
#define O_N    (NH*HD)           // 1024
#define M_ROWS (B_SZ*L_SEQ)      // 4096
#define EPSV   1e-6f

typedef __bf16  bf16x8_t  __attribute__((ext_vector_type(8)));
typedef float   f32x4_t   __attribute__((ext_vector_type(4)));
typedef unsigned short ushort8_t __attribute__((ext_vector_type(8)));

__device__ __forceinline__ unsigned short f2b(float f) {
    union { float f; uint32_t u; } v; v.f = f;
    uint32_t r = v.u + 0x7FFFu + ((v.u >> 16) & 1u);   // RNE to bf16
    return (unsigned short)(r >> 16);
}
__device__ __forceinline__ float b2f(unsigned short u) {
    union { uint32_t u; float f; } v; v.u = ((uint32_t)u) << 16;
    return v.f;
}

__device__ __forceinline__ void gload_lds16(const void* g, void* l) {
    __builtin_amdgcn_global_load_lds(
        (__attribute__((address_space(1))) void*)(g),
        (__attribute__((address_space(3))) void*)(l),
        16, 0, 0);
}

#define BARF() do { asm volatile("" ::: "memory"); \
                    __builtin_amdgcn_s_barrier();  \
                    asm volatile("" ::: "memory"); } while (0)

template <int N> __device__ __forceinline__ void vmcnt_wait() {
    if constexpr (N == 4)       asm volatile("s_waitcnt vmcnt(4)"  ::: "memory");
    else if constexpr (N == 5)  asm volatile("s_waitcnt vmcnt(5)"  ::: "memory");
    else if constexpr (N == 6)  asm volatile("s_waitcnt vmcnt(6)"  ::: "memory");
    else if constexpr (N == 8)  asm volatile("s_waitcnt vmcnt(8)"  ::: "memory");
    else if constexpr (N == 10) asm volatile("s_waitcnt vmcnt(10)" ::: "memory");
    else if constexpr (N == 12) asm volatile("s_waitcnt vmcnt(12)" ::: "memory");
    else                        asm volatile("s_waitcnt vmcnt(0)"  ::: "memory");
}

// ---------------- fp32 -> bf16 elementwise (8 elems/thread) ----------------
__global__ __launch_bounds__(256) void cvt_f32_bf16(const float* __restrict__ in,
                                                    unsigned short* __restrict__ out,
                                                    int n8) {
    int i = blockIdx.x * 256 + threadIdx.x;
    if (i >= n8) return;
    const float4* p = (const float4*)(in + (size_t)i * 8);
    float4 a = p[0], b = p[1];
    ushort8_t o;
    o[0]=f2b(a.x); o[1]=f2b(a.y); o[2]=f2b(a.z); o[3]=f2b(a.w);
    o[4]=f2b(b.x); o[5]=f2b(b.y); o[6]=f2b(b.z); o[7]=f2b(b.w);
    *(ushort8_t*)(out + (size_t)i * 8) = o;
}

// ------------- transpose fp32 (R x C) -> bf16 (C x R) ----------------------
__global__ __launch_bounds__(256) void transpose_f32_bf16(const float* __restrict__ in,
                                                          unsigned short* __restrict__ out,
                                                          int R, int C) {
    __shared__ float t[32][33];
    const int c0 = blockIdx.x * 32;
    const int r0 = blockIdx.y * 32;
    const int tx = threadIdx.x & 31;
    const int ty = threadIdx.x >> 5;
    #pragma unroll
    for (int i = 0; i < 32; i += 8)
        t[ty + i][tx] = in[(size_t)(r0 + ty + i) * C + c0 + tx];
    __syncthreads();
    #pragma unroll
    for (int i = 0; i < 32; i += 8)
        out[(size_t)(c0 + ty + i) * R + r0 + tx] = f2b(t[tx][ty + i]);
}

// ===========================================================================
// Single-barrier multi-buffered MFMA GEMM template (burst-read variant).
//   C[M,N] = A[M,K] * Bt[N,K]^T, bf16 in, OutT out.
//   8 waves as NWM x NWN, per-wave WM x WN, one barrier + one counted vmcnt
//   per K-tile. NBUF LDS buffers; stage(t+NBUF-1) issued during tile t.
//   Per tile: ALL KK*(AF+BF) ds_reads issued first (compiler emits partial
//   lgkmcnt so later reads complete under the first MFMA cluster), then the
//   staging gloads, then the MFMA clusters.
//   Hazard proof: stage(t) targets buf[(t+NBUF-1)%NBUF], never read during
//   tiles t..t+NBUF-2; a wave passes barrier(t+1) only after its tile-t
//   ds_reads completed (lgkm before its MFMAs). In-order vmcnt: at end of
//   tile t, wait<(NBUF-2)*RNDS> retires everything except the newest NBUF-2
//   stage groups => tile t+1 fully landed.
//   T2 swizzle (both-sides involution): BK=64 -> chunk^(row&7) on 128B rows;
//   BK=32 -> chunk^((row>>1)&3) on 64B rows.
// ===========================================================================
template <int BM, int BN, int BK, int NBUF, int NWM, int NWN, bool OBF16, typename OutT>
__global__ __launch_bounds__(512, 2)
void gemm_sb(const unsigned short* __restrict__ A,
             const unsigned short* __restrict__ Bt,
             OutT* __restrict__ C, int M, int N, int K) {
    constexpr int WM    = BM / NWM;
    constexpr int WN    = BN / NWN;
    constexpr int AF    = WM / 16;
    constexpr int BF    = WN / 16;
    constexpr int KK    = BK / 32;         // 16x16x32 MFMAs per k-chunk
    constexpr int BUF   = (BM + BN) * BK;  // shorts per buffer
    constexpr int ROWS  = 4096 / BK;       // rows covered per staging round
    constexpr int AR    = BM / ROWS;
    constexpr int BR    = BN / ROWS;
    constexpr int RNDS  = AR + BR;         // gloads/thread/tile
    constexpr int DEPTH = NBUF - 2;        // extra tiles in flight past t+1

    __shared__ unsigned short smem[NBUF * BUF];

    const int tid  = threadIdx.x;
    const int lane = tid & 63;
    const int wave = tid >> 6;
    const int wm   = wave / NWN;
    const int wn   = wave % NWN;
    const int fr   = lane & 15;
    const int fq   = lane >> 4;

    // XCD-aware bijective swizzle (gridDim.x % 8 == 0)
    const int nbx = N / BN;
    int bid = blockIdx.x;
    const int cpx = gridDim.x >> 3;
    bid = (bid & 7) * cpx + (bid >> 3);
    const int bx = bid % nbx, by = bid / nbx;
    const int m0 = by * BM, n0 = bx * BN;

    // staging address (pre-swizzled source; LDS dest stays linear)
    const int srow = tid / (BK / 8);
    const int sch  = tid & (BK / 8 - 1);
    const int ssw  = (BK == 64) ? (srow & 7) : ((srow >> 1) & 3);
    const int scs  = (sch ^ ssw) << 3;
    const unsigned short* gA = A  + (size_t)(m0 + srow) * K + scs;
    const unsigned short* gB = Bt + (size_t)(n0 + srow) * K + scs;

    // fragment-read swizzle phase
    const int frsw = (BK == 64) ? (fr & 7) : ((fr >> 1) & 3);

    f32x4_t acc[AF][BF];
    #pragma unroll
    for (int m = 0; m < AF; m++)
        #pragma unroll
        for (int n = 0; n < BF; n++)
            acc[m][n] = (f32x4_t){0.f, 0.f, 0.f, 0.f};

    const int NT = K / BK;

    auto STAGE = [&](int T) {
        const int pb = (T % NBUF) * BUF;
        #pragma unroll
        for (int q = 0; q < AR; ++q)
            gload_lds16(gA + (size_t)(q * ROWS) * K + (size_t)T * BK,
                        &smem[pb + q * 4096 + tid * 8]);
        #pragma unroll
        for (int q = 0; q < BR; ++q)
            gload_lds16(gB + (size_t)(q * ROWS) * K + (size_t)T * BK,
                        &smem[pb + BM * BK + q * 4096 + tid * 8]);
    };

    // prologue: stage tiles 0..NBUF-2; tile0 landed, rest in flight
    #pragma unroll
    for (int pt = 0; pt < NBUF - 1; ++pt) STAGE(pt);
    vmcnt_wait<DEPTH * RNDS>();

    for (int t = 0; t < NT; ++t) {
        const int sb = (t % NBUF) * BUF;
        BARF();   // the ONLY barrier per tile

        // burst: issue ALL fragment reads for the tile up front
        bf16x8_t aF[KK][AF], bF[KK][BF];
        #pragma unroll
        for (int kk = 0; kk < KK; ++kk) {
            const int cxk = (((kk * 4 + fq) ^ frsw)) << 3;
            #pragma unroll
            for (int mm = 0; mm < AF; ++mm)
                aF[kk][mm] = *(const bf16x8_t*)&smem[sb + (wm*WM + mm*16 + fr)*BK + cxk];
            #pragma unroll
            for (int nn = 0; nn < BF; ++nn)
                bF[kk][nn] = *(const bf16x8_t*)&smem[sb + BM*BK + (wn*WN + nn*16 + fr)*BK + cxk];
        }

        if (t + NBUF - 1 < NT) STAGE(t + NBUF - 1);

        #pragma unroll
        for (int kk = 0; kk < KK; ++kk) {
            __builtin_amdgcn_s_setprio(1);
            #pragma unroll
            for (int mm = 0; mm < AF; ++mm)
                #pragma unroll
                for (int nn = 0; nn < BF; ++nn)
                    acc[mm][nn] = __builtin_amdgcn_mfma_f32_16x16x32_bf16(
                        aF[kk][mm], bF[kk][nn], acc[mm][nn], 0, 0, 0);
            __builtin_amdgcn_s_setprio(0);
        }

        // counted drain: guarantee t+1 landed; deeper stages stay in flight
        if constexpr (DEPTH == 2) {
            if (t + 3 < NT)      { vmcnt_wait<2 * RNDS>(); }
            else if (t + 2 < NT) { vmcnt_wait<RNDS>(); }
            else if (t + 1 < NT) { vmcnt_wait<0>(); }
        } else {
            if (t + 2 < NT)      { vmcnt_wait<RNDS>(); }
            else if (t + 1 < NT) { vmcnt_wait<0>(); }
        }
    }

    // C/D layout (m89-verified): col = lane&15, row = (lane>>4)*4 + reg
    const int crow = m0 + wm * WM + fq * 4;
    const int ccol = n0 + wn * WN + fr;
    #pragma unroll
    for (int m = 0; m < AF; m++)
        #pragma unroll
        for (int n = 0; n < BF; n++)
            #pragma unroll
            for (int rr = 0; rr < 4; rr++) {
                const size_t idx = (size_t)(crow + m*16 + rr) * N + ccol + n*16;
                if constexpr (OBF16) C[idx] = (OutT)f2b(acc[m][n][rr]);
                else                 C[idx] = (OutT)acc[m][n][rr];
            }
}

// --------- fused RMSNorm + RoPE + 16-token block-diagonal attention --------
__global__ __launch_bounds__(64) void attn_fused(const unsigned short* __restrict__ qkv,
                                                 const float* __restrict__ cosb,
                                                 const float* __restrict__ sinb,
                                                 const float* __restrict__ qw,
                                                 const float* __restrict__ kw,
                                                 unsigned short* __restrict__ out) {
    const int h    = blockIdx.x & (NH - 1);
    const int blk  = (blockIdx.x >> 4) & 127;
    const int b    = blockIdx.x >> 11;
    const int pos0 = blk * 16;
    const int kvh  = h >> 2;

    const int lane = threadIdx.x;
    const int r    = lane >> 2;
    const int qp   = lane & 3;
    const int d0   = qp * 16;

    __shared__ float qs[16][65];
    __shared__ float ks[16][65];
    __shared__ float vs[16][65];
    __shared__ float ps[16][17];

    const size_t rowb = ((size_t)(b * L_SEQ + pos0 + r)) * NQKV;
    const unsigned short* qptr = qkv + (rowb + h) * HD + d0;
    const unsigned short* kptr = qkv + (rowb + NH + kvh) * HD + d0;
    const unsigned short* vptr = qkv + (rowb + NH + NKV + kvh) * HD + d0;
    const size_t csrow = ((size_t)(b * L_SEQ + pos0 + r)) * HD + d0;

    float q[16], k[16], v[16], cs[16], sn[16];
    {
        ushort8_t q0 = *(const ushort8_t*)&qptr[0], q1 = *(const ushort8_t*)&qptr[8];
        ushort8_t k0 = *(const ushort8_t*)&kptr[0], k1 = *(const ushort8_t*)&kptr[8];
        ushort8_t v0 = *(const ushort8_t*)&vptr[0], v1 = *(const ushort8_t*)&vptr[8];
        #pragma unroll
        for (int i = 0; i < 8; i++) {
            q[i] = b2f(q0[i]); q[i+8] = b2f(q1[i]);
            k[i] = b2f(k0[i]); k[i+8] = b2f(k1[i]);
            v[i] = b2f(v0[i]); v[i+8] = b2f(v1[i]);
        }
        #pragma unroll
        for (int i = 0; i < 16; i += 4) {
            *(float4*)&cs[i] = *(const float4*)&cosb[csrow + i];
            *(float4*)&sn[i] = *(const float4*)&sinb[csrow + i];
        }
    }

    float sq = 0.f, sk = 0.f;
    #pragma unroll
    for (int i = 0; i < 16; i++) { sq += q[i]*q[i]; sk += k[i]*k[i]; }
    sq += __shfl_xor(sq, 1); sq += __shfl_xor(sq, 2);
    sk += __shfl_xor(sk, 1); sk += __shfl_xor(sk, 2);
    const float rq = rsqrtf(sq * (1.f / HD) + EPSV);
    const float rk = rsqrtf(sk * (1.f / HD) + EPSV);

    const float sgn = (qp < 2) ? -1.f : 1.f;
    #pragma unroll
    for (int i = 0; i < 16; i++) {
        float qn = q[i] * rq * qw[d0 + i];
        float kn = k[i] * rk * kw[d0 + i];
        float qo = __shfl_xor(qn, 2);
        float ko = __shfl_xor(kn, 2);
        qs[r][d0 + i] = qn * cs[i] + sgn * qo * sn[i];
        ks[r][d0 + i] = kn * cs[i] + sgn * ko * sn[i];
        vs[r][d0 + i] = v[i];
    }
    __syncthreads();

    float sc[4] = {0.f, 0.f, 0.f, 0.f};
    for (int d = 0; d < 64; d++) {
        const float qd = qs[r][d];
        sc[0] += qd * ks[qp     ][d];
        sc[1] += qd * ks[qp +  4][d];
        sc[2] += qd * ks[qp +  8][d];
        sc[3] += qd * ks[qp + 12][d];
    }
    #pragma unroll
    for (int cc = 0; cc < 4; cc++) {
        const int c = qp + cc * 4;
        sc[cc] = (c <= r) ? sc[cc] * 0.125f : -3.0e38f;
    }
    float mx = fmaxf(fmaxf(sc[0], sc[1]), fmaxf(sc[2], sc[3]));
    mx = fmaxf(mx, __shfl_xor(mx, 1));
    mx = fmaxf(mx, __shfl_xor(mx, 2));
    float e[4], sum = 0.f;
    #pragma unroll
    for (int cc = 0; cc < 4; cc++) { e[cc] = __expf(sc[cc] - mx); sum += e[cc]; }
    sum += __shfl_xor(sum, 1); sum += __shfl_xor(sum, 2);
    const float inv = 1.f / sum;
    #pragma unroll
    for (int cc = 0; cc < 4; cc++) ps[r][qp + cc * 4] = e[cc] * inv;
    __syncthreads();

    float o[16];
    #pragma unroll
    for (int i = 0; i < 16; i++) o[i] = 0.f;
    #pragma unroll
    for (int c = 0; c < 16; c++) {
        const float p = ps[r][c];
        #pragma unroll
        for (int i = 0; i < 16; i++) o[i] += p * vs[c][d0 + i];
    }

    __attribute__((aligned(16))) unsigned short ob[16];
    #pragma unroll
    for (int i = 0; i < 16; i++) ob[i] = f2b(o[i]);
    unsigned short* optr = out + (((size_t)(b * L_SEQ + pos0 + r) * NH + h) * HD) + d0;
    *(uint4*)optr       = *(uint4*)&ob[0];
    *((uint4*)optr + 1) = *(uint4*)&ob[8];
}

// ---------------------------------------------------------------------------
extern "C" void kernel_launch(void* const* d_in, const int* in_sizes, int n_in,
                              void* d_out, int out_size, void* d_ws, size_t ws_size,
                              hipStream_t stream) {
    const float* hid  = (const float*)d_in[0];
    const float* cosb = (const float*)d_in[2];
    const float* sinb = (const float*)d_in[3];
    const float* Wqkv = (const float*)d_in[4];
    const float* Wo   = (const float*)d_in[5];
    const float* qw   = (const float*)d_in[6];
    const float* kw   = (const float*)d_in[7];
    float* outp = (float*)d_out;

    char* ws = (char*)d_ws;
    unsigned short* Hb    = (unsigned short*)ws; ws += (size_t)M_ROWS * HID * 2;
    unsigned short* WqkvT = (unsigned short*)ws; ws += (size_t)QKV_N * HID * 2;
    unsigned short* WoT   = (unsigned short*)ws; ws += (size_t)HID * O_N * 2;
    unsigned short* qkvb  = (unsigned short*)ws; ws += (size_t)M_ROWS * QKV_N * 2;
    unsigned short* attnb = (unsigned short*)ws;

    {
        int n8 = (M_ROWS * HID) / 8;
        cvt_f32_bf16<<<(n8 + 255) / 256, 256, 0, stream>>>(hid, Hb, n8);
    }
    transpose_f32_bf16<<<dim3(QKV_N / 32, HID / 32), 256, 0, stream>>>(Wqkv, WqkvT, HID, QKV_N);
    transpose_f32_bf16<<<dim3(HID / 32, O_N / 32),  256, 0, stream>>>(Wo,   WoT,   O_N, HID);

    // GEMM1: qkv = H @ Wqkv (4096 x 1536 x 4096)
    //   256x128 tiles (MFMA-bound geometry: wave 64x64, 1/AF+1/BF=0.5),
    //   BK=64, 3 buffers (144KB), 192 blocks, 4Mx2N waves,
    //   single barrier + burst reads + vmcnt(6) per tile
    gemm_sb<256, 128, 64, 3, 4, 2, true, unsigned short>
        <<<dim3((M_ROWS / 256) * (QKV_N / 128)), 512, 0, stream>>>
        (Hb, WqkvT, qkvb, M_ROWS, QKV_N, HID);

    // fused rmsnorm + rope + block-diag attention (bf16 in/out)
    attn_fused<<<dim3(B_SZ * (L_SEQ / 16) * NH), 64, 0, stream>>>(qkvb, cosb, sinb, qw, kw, attnb);

    // GEMM2 (unchanged): out = attn @ Wo (4096 x 4096 x 1024)
    //   256x256 tiles, BK=32, 4 buffers (128KB), 256 blocks (1/CU),
    //   waves 2Mx4N (128x64), single barrier + vmcnt(8)/tile
    gemm_sb<256, 256, 32, 4, 2, 4, false, float>
        <<<dim3((M_ROWS / 256) * (HID / 256)), 512, 0, stream>>>
        (attnb, WoT, outp, M_ROWS, HID, O_N);
}

// Round 9
// 151.872 us; speedup vs baseline: 1.0033x; 1.0033x over previous
//
#include <hip/hip_runtime.h>
#include <hip/hip_bf16.h>
#include <cstdint>

// Problem constants (from reference)
#define B_SZ   2
#define L_SEQ  2048
#define HID    4096
#define NH     16
#define NKV    4
#define HD     64
#define NQKV   (NH + 2*NKV)      // 24
#define QKV_N  (NQKV*HD)         // 1536
#define O_N    (NH*HD)           // 1024
#define M_ROWS (B_SZ*L_SEQ)      // 4096
#define EPSV   1e-6f

typedef __bf16  bf16x8_t  __attribute__((ext_vector_type(8)));
typedef float   f32x4_t   __attribute__((ext_vector_type(4)));
typedef unsigned short ushort8_t __attribute__((ext_vector_type(8)));

__device__ __forceinline__ unsigned short f2b(float f) {
    union { float f; uint32_t u; } v; v.f = f;
    uint32_t r = v.u + 0x7FFFu + ((v.u >> 16) & 1u);   // RNE to bf16
    return (unsigned short)(r >> 16);
}
__device__ __forceinline__ float b2f(unsigned short u) {
    union { uint32_t u; float f; } v; v.u = ((uint32_t)u) << 16;
    return v.f;
}

__device__ __forceinline__ void gload_lds16(const void* g, void* l) {
    __builtin_amdgcn_global_load_lds(
        (__attribute__((address_space(1))) void*)(g),
        (__attribute__((address_space(3))) void*)(l),
        16, 0, 0);
}

#define BARF() do { asm volatile("" ::: "memory"); \
                    __builtin_amdgcn_s_barrier();  \
                    asm volatile("" ::: "memory"); } while (0)

template <int N> __device__ __forceinline__ void vmcnt_wait() {
    if constexpr (N == 4)       asm volatile("s_waitcnt vmcnt(4)"  ::: "memory");
    else if constexpr (N == 5)  asm volatile("s_waitcnt vmcnt(5)"  ::: "memory");
    else if constexpr (N == 6)  asm volatile("s_waitcnt vmcnt(6)"  ::: "memory");
    else if constexpr (N == 8)  asm volatile("s_waitcnt vmcnt(8)"  ::: "memory");
    else if constexpr (N == 10) asm volatile("s_waitcnt vmcnt(10)" ::: "memory");
    else if constexpr (N == 12) asm volatile("s_waitcnt vmcnt(12)" ::: "memory");
    else                        asm volatile("s_waitcnt vmcnt(0)"  ::: "memory");
}

// ---------------- fp32 -> bf16 elementwise (8 elems/thread) ----------------
__global__ __launch_bounds__(256) void cvt_f32_bf16(const float* __restrict__ in,
                                                    unsigned short* __restrict__ out,
                                                    int n8) {
    int i = blockIdx.x * 256 + threadIdx.x;
    if (i >= n8) return;
    const float4* p = (const float4*)(in + (size_t)i * 8);
    float4 a = p[0], b = p[1];
    ushort8_t o;
    o[0]=f2b(a.x); o[1]=f2b(a.y); o[2]=f2b(a.z); o[3]=f2b(a.w);
    o[4]=f2b(b.x); o[5]=f2b(b.y); o[6]=f2b(b.z); o[7]=f2b(b.w);
    *(ushort8_t*)(out + (size_t)i * 8) = o;
}

// ------------- transpose fp32 (R x C) -> bf16 (C x R) ----------------------
__global__ __launch_bounds__(256) void transpose_f32_bf16(const float* __restrict__ in,
                                                          unsigned short* __restrict__ out,
                                                          int R, int C) {
    __shared__ float t[32][33];
    const int c0 = blockIdx.x * 32;
    const int r0 = blockIdx.y * 32;
    const int tx = threadIdx.x & 31;
    const int ty = threadIdx.x >> 5;
    #pragma unroll
    for (int i = 0; i < 32; i += 8)
        t[ty + i][tx] = in[(size_t)(r0 + ty + i) * C + c0 + tx];
    __syncthreads();
    #pragma unroll
    for (int i = 0; i < 32; i += 8)
        out[(size_t)(c0 + ty + i) * R + r0 + tx] = f2b(t[tx][ty + i]);
}

// ===========================================================================
// Single-barrier multi-buffered MFMA GEMM template.
//   C[M,N] = A[M,K] * Bt[N,K]^T, bf16 in, OutT out.
//   8 waves as NWM x NWN, per-wave WM x WN, one barrier + one counted vmcnt
//   per K-tile. NBUF LDS buffers; stage(t+NBUF-1) issued during tile t.
//   BURST=true: all KK*(AF+BF) ds_reads issued before the MFMA clusters
//   (compiler partial-lgkmcnt overlaps late reads under early MFMAs).
//   BURST=false: per-kk read->MFMA (round-6/7 proven path).
//   Hazard proof: stage(t) targets buf[(t+NBUF-1)%NBUF], never read during
//   tiles t..t+NBUF-2; a wave passes barrier(t+1) only after its tile-t
//   ds_reads completed (lgkm before its MFMAs). In-order vmcnt: at end of
//   tile t, wait<(NBUF-2)*RNDS> retires all but the newest NBUF-2 stage
//   groups => tile t+1 fully landed.
//   T2 swizzle (both-sides involution): BK=64 -> chunk^(row&7) on 128B rows;
//   BK=32 -> chunk^((row>>1)&3) on 64B rows.
// ===========================================================================
template <int BM, int BN, int BK, int NBUF, int NWM, int NWN, bool BURST,
          bool OBF16, typename OutT>
__global__ __launch_bounds__(512, 2)
void gemm_sb(const unsigned short* __restrict__ A,
             const unsigned short* __restrict__ Bt,
             OutT* __restrict__ C, int M, int N, int K) {
    constexpr int WM    = BM / NWM;
    constexpr int WN    = BN / NWN;
    constexpr int AF    = WM / 16;
    constexpr int BF    = WN / 16;
    constexpr int KK    = BK / 32;         // 16x16x32 MFMAs per k-chunk
    constexpr int BUF   = (BM + BN) * BK;  // shorts per buffer
    constexpr int ROWS  = 4096 / BK;       // rows covered per staging round
    constexpr int AR    = BM / ROWS;
    constexpr int BR    = BN / ROWS;
    constexpr int RNDS  = AR + BR;         // gloads/thread/tile
    constexpr int DEPTH = NBUF - 2;        // extra tiles in flight past t+1

    __shared__ unsigned short smem[NBUF * BUF];

    const int tid  = threadIdx.x;
    const int lane = tid & 63;
    const int wave = tid >> 6;
    const int wm   = wave / NWN;
    const int wn   = wave % NWN;
    const int fr   = lane & 15;
    const int fq   = lane >> 4;

    // XCD-aware bijective swizzle (gridDim.x % 8 == 0)
    const int nbx = N / BN;
    int bid = blockIdx.x;
    const int cpx = gridDim.x >> 3;
    bid = (bid & 7) * cpx + (bid >> 3);
    const int bx = bid % nbx, by = bid / nbx;
    const int m0 = by * BM, n0 = bx * BN;

    // staging address (pre-swizzled source; LDS dest stays linear)
    const int srow = tid / (BK / 8);
    const int sch  = tid & (BK / 8 - 1);
    const int ssw  = (BK == 64) ? (srow & 7) : ((srow >> 1) & 3);
    const int scs  = (sch ^ ssw) << 3;
    const unsigned short* gA = A  + (size_t)(m0 + srow) * K + scs;
    const unsigned short* gB = Bt + (size_t)(n0 + srow) * K + scs;

    // fragment-read swizzle phase
    const int frsw = (BK == 64) ? (fr & 7) : ((fr >> 1) & 3);

    f32x4_t acc[AF][BF];
    #pragma unroll
    for (int m = 0; m < AF; m++)
        #pragma unroll
        for (int n = 0; n < BF; n++)
            acc[m][n] = (f32x4_t){0.f, 0.f, 0.f, 0.f};

    const int NT = K / BK;

    auto STAGE = [&](int T) {
        const int pb = (T % NBUF) * BUF;
        #pragma unroll
        for (int q = 0; q < AR; ++q)
            gload_lds16(gA + (size_t)(q * ROWS) * K + (size_t)T * BK,
                        &smem[pb + q * 4096 + tid * 8]);
        #pragma unroll
        for (int q = 0; q < BR; ++q)
            gload_lds16(gB + (size_t)(q * ROWS) * K + (size_t)T * BK,
                        &smem[pb + BM * BK + q * 4096 + tid * 8]);
    };

    // prologue: stage tiles 0..NBUF-2; tile0 landed, rest in flight
    #pragma unroll
    for (int pt = 0; pt < NBUF - 1; ++pt) STAGE(pt);
    vmcnt_wait<DEPTH * RNDS>();

    for (int t = 0; t < NT; ++t) {
        const int sb = (t % NBUF) * BUF;
        BARF();   // the ONLY barrier per tile

        if constexpr (BURST) {
            bf16x8_t aF[KK][AF], bF[KK][BF];
            #pragma unroll
            for (int kk = 0; kk < KK; ++kk) {
                const int cxk = (((kk * 4 + fq) ^ frsw)) << 3;
                #pragma unroll
                for (int mm = 0; mm < AF; ++mm)
                    aF[kk][mm] = *(const bf16x8_t*)&smem[sb + (wm*WM + mm*16 + fr)*BK + cxk];
                #pragma unroll
                for (int nn = 0; nn < BF; ++nn)
                    bF[kk][nn] = *(const bf16x8_t*)&smem[sb + BM*BK + (wn*WN + nn*16 + fr)*BK + cxk];
            }
            if (t + NBUF - 1 < NT) STAGE(t + NBUF - 1);
            #pragma unroll
            for (int kk = 0; kk < KK; ++kk) {
                __builtin_amdgcn_s_setprio(1);
                #pragma unroll
                for (int mm = 0; mm < AF; ++mm)
                    #pragma unroll
                    for (int nn = 0; nn < BF; ++nn)
                        acc[mm][nn] = __builtin_amdgcn_mfma_f32_16x16x32_bf16(
                            aF[kk][mm], bF[kk][nn], acc[mm][nn], 0, 0, 0);
                __builtin_amdgcn_s_setprio(0);
            }
        } else {
            #pragma unroll
            for (int kk = 0; kk < KK; ++kk) {
                const int cxk = (((kk * 4 + fq) ^ frsw)) << 3;
                bf16x8_t aF[AF], bF[BF];
                #pragma unroll
                for (int mm = 0; mm < AF; ++mm)
                    aF[mm] = *(const bf16x8_t*)&smem[sb + (wm*WM + mm*16 + fr)*BK + cxk];
                #pragma unroll
                for (int nn = 0; nn < BF; ++nn)
                    bF[nn] = *(const bf16x8_t*)&smem[sb + BM*BK + (wn*WN + nn*16 + fr)*BK + cxk];

                if (kk == 0 && t + NBUF - 1 < NT) STAGE(t + NBUF - 1);

                __builtin_amdgcn_s_setprio(1);
                #pragma unroll
                for (int mm = 0; mm < AF; ++mm)
                    #pragma unroll
                    for (int nn = 0; nn < BF; ++nn)
                        acc[mm][nn] = __builtin_amdgcn_mfma_f32_16x16x32_bf16(
                            aF[mm], bF[nn], acc[mm][nn], 0, 0, 0);
                __builtin_amdgcn_s_setprio(0);
            }
        }

        // counted drain: guarantee t+1 landed; deeper stages stay in flight
        if constexpr (DEPTH == 2) {
            if (t + 3 < NT)      { vmcnt_wait<2 * RNDS>(); }
            else if (t + 2 < NT) { vmcnt_wait<RNDS>(); }
            else if (t + 1 < NT) { vmcnt_wait<0>(); }
        } else {
            if (t + 2 < NT)      { vmcnt_wait<RNDS>(); }
            else if (t + 1 < NT) { vmcnt_wait<0>(); }
        }
    }

    // C/D layout (m89-verified): col = lane&15, row = (lane>>4)*4 + reg
    const int crow = m0 + wm * WM + fq * 4;
    const int ccol = n0 + wn * WN + fr;
    #pragma unroll
    for (int m = 0; m < AF; m++)
        #pragma unroll
        for (int n = 0; n < BF; n++)
            #pragma unroll
            for (int rr = 0; rr < 4; rr++) {
                const size_t idx = (size_t)(crow + m*16 + rr) * N + ccol + n*16;
                if constexpr (OBF16) C[idx] = (OutT)f2b(acc[m][n][rr]);
                else                 C[idx] = (OutT)acc[m][n][rr];
            }
}

// --------- fused RMSNorm + RoPE + 16-token block-diagonal attention --------
__global__ __launch_bounds__(64) void attn_fused(const unsigned short* __restrict__ qkv,
                                                 const float* __restrict__ cosb,
                                                 const float* __restrict__ sinb,
                                                 const float* __restrict__ qw,
                                                 const float* __restrict__ kw,
                                                 unsigned short* __restrict__ out) {
    const int h    = blockIdx.x & (NH - 1);
    const int blk  = (blockIdx.x >> 4) & 127;
    const int b    = blockIdx.x >> 11;
    const int pos0 = blk * 16;
    const int kvh  = h >> 2;

    const int lane = threadIdx.x;
    const int r    = lane >> 2;
    const int qp   = lane & 3;
    const int d0   = qp * 16;

    __shared__ float qs[16][65];
    __shared__ float ks[16][65];
    __shared__ float vs[16][65];
    __shared__ float ps[16][17];

    const size_t rowb = ((size_t)(b * L_SEQ + pos0 + r)) * NQKV;
    const unsigned short* qptr = qkv + (rowb + h) * HD + d0;
    const unsigned short* kptr = qkv + (rowb + NH + kvh) * HD + d0;
    const unsigned short* vptr = qkv + (rowb + NH + NKV + kvh) * HD + d0;
    const size_t csrow = ((size_t)(b * L_SEQ + pos0 + r)) * HD + d0;

    float q[16], k[16], v[16], cs[16], sn[16];
    {
        ushort8_t q0 = *(const ushort8_t*)&qptr[0], q1 = *(const ushort8_t*)&qptr[8];
        ushort8_t k0 = *(const ushort8_t*)&kptr[0], k1 = *(const ushort8_t*)&kptr[8];
        ushort8_t v0 = *(const ushort8_t*)&vptr[0], v1 = *(const ushort8_t*)&vptr[8];
        #pragma unroll
        for (int i = 0; i < 8; i++) {
            q[i] = b2f(q0[i]); q[i+8] = b2f(q1[i]);
            k[i] = b2f(k0[i]); k[i+8] = b2f(k1[i]);
            v[i] = b2f(v0[i]); v[i+8] = b2f(v1[i]);
        }
        #pragma unroll
        for (int i = 0; i < 16; i += 4) {
            *(float4*)&cs[i] = *(const float4*)&cosb[csrow + i];
            *(float4*)&sn[i] = *(const float4*)&sinb[csrow + i];
        }
    }

    float sq = 0.f, sk = 0.f;
    #pragma unroll
    for (int i = 0; i < 16; i++) { sq += q[i]*q[i]; sk += k[i]*k[i]; }
    sq += __shfl_xor(sq, 1); sq += __shfl_xor(sq, 2);
    sk += __shfl_xor(sk, 1); sk += __shfl_xor(sk, 2);
    const float rq = rsqrtf(sq * (1.f / HD) + EPSV);
    const float rk = rsqrtf(sk * (1.f / HD) + EPSV);

    const float sgn = (qp < 2) ? -1.f : 1.f;
    #pragma unroll
    for (int i = 0; i < 16; i++) {
        float qn = q[i] * rq * qw[d0 + i];
        float kn = k[i] * rk * kw[d0 + i];
        float qo = __shfl_xor(qn, 2);
        float ko = __shfl_xor(kn, 2);
        qs[r][d0 + i] = qn * cs[i] + sgn * qo * sn[i];
        ks[r][d0 + i] = kn * cs[i] + sgn * ko * sn[i];
        vs[r][d0 + i] = v[i];
    }
    __syncthreads();

    float sc[4] = {0.f, 0.f, 0.f, 0.f};
    for (int d = 0; d < 64; d++) {
        const float qd = qs[r][d];
        sc[0] += qd * ks[qp     ][d];
        sc[1] += qd * ks[qp +  4][d];
        sc[2] += qd * ks[qp +  8][d];
        sc[3] += qd * ks[qp + 12][d];
    }
    #pragma unroll
    for (int cc = 0; cc < 4; cc++) {
        const int c = qp + cc * 4;
        sc[cc] = (c <= r) ? sc[cc] * 0.125f : -3.0e38f;
    }
    float mx = fmaxf(fmaxf(sc[0], sc[1]), fmaxf(sc[2], sc[3]));
    mx = fmaxf(mx, __shfl_xor(mx, 1));
    mx = fmaxf(mx, __shfl_xor(mx, 2));
    float e[4], sum = 0.f;
    #pragma unroll
    for (int cc = 0; cc < 4; cc++) { e[cc] = __expf(sc[cc] - mx); sum += e[cc]; }
    sum += __shfl_xor(sum, 1); sum += __shfl_xor(sum, 2);
    const float inv = 1.f / sum;
    #pragma unroll
    for (int cc = 0; cc < 4; cc++) ps[r][qp + cc * 4] = e[cc] * inv;
    __syncthreads();

    float o[16];
    #pragma unroll
    for (int i = 0; i < 16; i++) o[i] = 0.f;
    #pragma unroll
    for (int c = 0; c < 16; c++) {
        const float p = ps[r][c];
        #pragma unroll
        for (int i = 0; i < 16; i++) o[i] += p * vs[c][d0 + i];
    }

    __attribute__((aligned(16))) unsigned short ob[16];
    #pragma unroll
    for (int i = 0; i < 16; i++) ob[i] = f2b(o[i]);
    unsigned short* optr = out + (((size_t)(b * L_SEQ + pos0 + r) * NH + h) * HD) + d0;
    *(uint4*)optr       = *(uint4*)&ob[0];
    *((uint4*)optr + 1) = *(uint4*)&ob[8];
}

// ---------------------------------------------------------------------------
extern "C" void kernel_launch(void* const* d_in, const int* in_sizes, int n_in,
                              void* d_out, int out_size, void* d_ws, size_t ws_size,
                              hipStream_t stream) {
    const float* hid  = (const float*)d_in[0];
    const float* cosb = (const float*)d_in[2];
    const float* sinb = (const float*)d_in[3];
    const float* Wqkv = (const float*)d_in[4];
    const float* Wo   = (const float*)d_in[5];
    const float* qw   = (const float*)d_in[6];
    const float* kw   = (const float*)d_in[7];
    float* outp = (float*)d_out;

    char* ws = (char*)d_ws;
    unsigned short* Hb    = (unsigned short*)ws; ws += (size_t)M_ROWS * HID * 2;
    unsigned short* WqkvT = (unsigned short*)ws; ws += (size_t)QKV_N * HID * 2;
    unsigned short* WoT   = (unsigned short*)ws; ws += (size_t)HID * O_N * 2;
    unsigned short* qkvb  = (unsigned short*)ws; ws += (size_t)M_ROWS * QKV_N * 2;
    unsigned short* attnb = (unsigned short*)ws;

    {
        int n8 = (M_ROWS * HID) / 8;
        cvt_f32_bf16<<<(n8 + 255) / 256, 256, 0, stream>>>(hid, Hb, n8);
    }
    transpose_f32_bf16<<<dim3(QKV_N / 32, HID / 32), 256, 0, stream>>>(Wqkv, WqkvT, HID, QKV_N);
    transpose_f32_bf16<<<dim3(HID / 32, O_N / 32),  256, 0, stream>>>(Wo,   WoT,   O_N, HID);

    // GEMM1 (revert to round-6 best): qkv = H @ Wqkv (4096 x 1536 x 4096)
    //   128x192 tiles, BK=64, NBUF=3 (120KB), 256 blocks (full coverage),
    //   2Mx4N waves, per-kk reads
    gemm_sb<128, 192, 64, 3, 2, 4, false, true, unsigned short>
        <<<dim3((M_ROWS / 128) * (QKV_N / 192)), 512, 0, stream>>>
        (Hb, WqkvT, qkvb, M_ROWS, QKV_N, HID);

    // fused rmsnorm + rope + block-diag attention (bf16 in/out)
    attn_fused<<<dim3(B_SZ * (L_SEQ / 16) * NH), 64, 0, stream>>>(qkvb, cosb, sinb, qw, kw, attnb);

    // GEMM2 (measured-best per-CU config, now at FULL coverage):
    //   out = attn @ Wo (4096 x 4096 x 1024)
    //   256x128 tiles, BK=64, NBUF=3 (144KB), 512 blocks = 2 rounds/CU,
    //   4Mx2N waves (64x64/wave), burst reads, vmcnt(6)/tile
    gemm_sb<256, 128, 64, 3, 4, 2, true, false, float>
        <<<dim3((M_ROWS / 256) * (HID / 128)), 512, 0, stream>>>
        (attnb, WoT, outp, M_ROWS, HID, O_N);
}

// Round 10
// 148.117 us; speedup vs baseline: 1.0288x; 1.0254x over previous
//
#include <hip/hip_runtime.h>
#include <hip/hip_bf16.h>
#include <cstdint>

// Problem constants (from reference)
#define B_SZ   2
#define L_SEQ  2048
#define HID    4096
#define NH     16
#define NKV    4
#define HD     64
#define NQKV   (NH + 2*NKV)      // 24
#define QKV_N  (NQKV*HD)         // 1536
#define O_N    (NH*HD)           // 1024
#define M_ROWS (B_SZ*L_SEQ)      // 4096
#define EPSV   1e-6f

typedef __bf16  bf16x8_t  __attribute__((ext_vector_type(8)));
typedef float   f32x4_t   __attribute__((ext_vector_type(4)));
typedef unsigned short ushort8_t __attribute__((ext_vector_type(8)));

__device__ __forceinline__ unsigned short f2b(float f) {
    union { float f; uint32_t u; } v; v.f = f;
    uint32_t r = v.u + 0x7FFFu + ((v.u >> 16) & 1u);   // RNE to bf16
    return (unsigned short)(r >> 16);
}
__device__ __forceinline__ float b2f(unsigned short u) {
    union { uint32_t u; float f; } v; v.u = ((uint32_t)u) << 16;
    return v.f;
}

__device__ __forceinline__ void gload_lds16(const void* g, void* l) {
    __builtin_amdgcn_global_load_lds(
        (__attribute__((address_space(1))) void*)(g),
        (__attribute__((address_space(3))) void*)(l),
        16, 0, 0);
}

#define BARF() do { asm volatile("" ::: "memory"); \
                    __builtin_amdgcn_s_barrier();  \
                    asm volatile("" ::: "memory"); } while (0)
#define FENCE() asm volatile("" ::: "memory")
#define LGKM0() asm volatile("s_waitcnt lgkmcnt(0)" ::: "memory")

template <int N> __device__ __forceinline__ void vmcnt_wait() {
    if constexpr (N == 3)       asm volatile("s_waitcnt vmcnt(3)"  ::: "memory");
    else if constexpr (N == 4)  asm volatile("s_waitcnt vmcnt(4)"  ::: "memory");
    else if constexpr (N == 5)  asm volatile("s_waitcnt vmcnt(5)"  ::: "memory");
    else if constexpr (N == 6)  asm volatile("s_waitcnt vmcnt(6)"  ::: "memory");
    else if constexpr (N == 8)  asm volatile("s_waitcnt vmcnt(8)"  ::: "memory");
    else if constexpr (N == 12) asm volatile("s_waitcnt vmcnt(12)" ::: "memory");
    else                        asm volatile("s_waitcnt vmcnt(0)"  ::: "memory");
}

// ---- merged weight transposes: fp32 (R x C) -> bf16 (C x R), both weights --
__global__ __launch_bounds__(256) void transpose_both(const float* __restrict__ Wqkv,
                                                      unsigned short* __restrict__ WqkvT,
                                                      const float* __restrict__ Wo,
                                                      unsigned short* __restrict__ WoT) {
    __shared__ float t[32][33];
    // Wqkv: R=HID(4096), C=QKV_N(1536): grid 48 x 128 = 6144 blocks
    // Wo:   R=O_N(1024),  C=HID(4096):  grid 128 x 32 = 4096 blocks
    const float* in;
    unsigned short* out;
    int R, C, bx, by;
    if (blockIdx.x < 6144) {
        in = Wqkv; out = WqkvT; R = HID; C = QKV_N;
        bx = blockIdx.x % 48; by = blockIdx.x / 48;
    } else {
        int b = blockIdx.x - 6144;
        in = Wo; out = WoT; R = O_N; C = HID;
        bx = b % 128; by = b / 128;
    }
    const int c0 = bx * 32;
    const int r0 = by * 32;
    const int tx = threadIdx.x & 31;
    const int ty = threadIdx.x >> 5;
    #pragma unroll
    for (int i = 0; i < 32; i += 8)
        t[ty + i][tx] = in[(size_t)(r0 + ty + i) * C + c0 + tx];
    __syncthreads();
    #pragma unroll
    for (int i = 0; i < 32; i += 8)
        out[(size_t)(c0 + ty + i) * R + r0 + tx] = f2b(t[tx][ty + i]);
}

// ===========================================================================
// GEMM1 with fused fp32->bf16 A-conversion (T14 reg-staging for A).
//   qkvb[M,N] = cvt_bf16(Hf32[M,K]) @ WqkvT[N,K]^T,  M=4096 N=1536 K=4096.
//   128x192 tile, BK=64, NBUF=3 (120KB), 8 waves 2Mx4N (64x48), per-kk reads,
//   single barrier per K-tile (round-6 proven structure).
//   A-staging: float4 loads (t+2) issued at kk=0 BEFORE B's global_load_lds
//   (fence-pinned order), cvt+ds_write AFTER the MFMA clusters into the
//   swizzled LDS address of buf[(t+2)%3] (free during tile t). lgkmcnt(0)
//   before the next raw barrier makes the ds_writes cross-wave visible.
//   B-staging: gload_lds with pre-swizzled source (unchanged).
//   Drain logic: compiler-inserted vmcnt before the cvt-use retires A(t+2)
//   AND (in-order, older) B(t+1) => no manual end-of-tile vmcnt in steady
//   state; vmcnt(0) once at t=NT-2 for B(NT-1).
// ===========================================================================
#define G1_BM   128
#define G1_BN   192
#define G1_BUF  ((G1_BM + G1_BN) * 64)     // 20480 shorts / buffer
#define G1_NT   (HID / 64)                 // 64

__global__ __launch_bounds__(512, 2)
void gemm1_f32a(const float* __restrict__ A32,
                const unsigned short* __restrict__ Bt,
                unsigned short* __restrict__ C) {
    constexpr int AF = 4, BF = 3;          // wave 64x48
    __shared__ unsigned short smem[3 * G1_BUF];   // 120 KiB

    const int tid  = threadIdx.x;
    const int lane = tid & 63;
    const int wave = tid >> 6;
    const int wm   = wave >> 2;            // 0..1 (M half)
    const int wn   = wave & 3;             // 0..3 (N quarter)
    const int fr   = lane & 15;
    const int fq   = lane >> 4;

    const int nbx = QKV_N / G1_BN;         // 8
    int bid = blockIdx.x;
    const int cpx = gridDim.x >> 3;
    bid = (bid & 7) * cpx + (bid >> 3);
    const int bx = bid % nbx, by = bid / nbx;
    const int m0 = by * G1_BM, n0 = bx * G1_BN;

    // A staging (fp32, reg): thread covers row srowA (+64 for round 1),
    // 8 fp32 at chunk ca
    const int srowA = tid >> 3;            // 0..63
    const int ca    = tid & 7;
    const float* gAf = A32 + (size_t)(m0 + srowA) * HID + ca * 8;
    const int   wAsh = (ca ^ (srowA & 7)) << 3;   // swizzled LDS chunk (shorts)

    // B staging (bf16, gload_lds, pre-swizzled source)
    const int srow = tid >> 3;
    const int scs  = ((tid & 7) ^ (srow & 7)) << 3;
    const unsigned short* gB = Bt + (size_t)(n0 + srow) * HID + scs;

    const int frsw = fr & 7;

    f32x4_t acc[AF][BF];
    #pragma unroll
    for (int m = 0; m < AF; m++)
        #pragma unroll
        for (int n = 0; n < BF; n++)
            acc[m][n] = (f32x4_t){0.f, 0.f, 0.f, 0.f};

    auto LOAD_A = [&](int T, float4 av[2][2]) {
        const float* g = gAf + (size_t)T * 64;
        #pragma unroll
        for (int q = 0; q < 2; ++q) {
            av[q][0] = *(const float4*)(g + (size_t)q * 64 * HID);
            av[q][1] = *(const float4*)(g + (size_t)q * 64 * HID + 4);
        }
    };
    auto WRITE_A = [&](int T, float4 av[2][2]) {
        const int pb = (T % 3) * G1_BUF;
        #pragma unroll
        for (int q = 0; q < 2; ++q) {
            ushort8_t o;
            o[0] = f2b(av[q][0].x); o[1] = f2b(av[q][0].y);
            o[2] = f2b(av[q][0].z); o[3] = f2b(av[q][0].w);
            o[4] = f2b(av[q][1].x); o[5] = f2b(av[q][1].y);
            o[6] = f2b(av[q][1].z); o[7] = f2b(av[q][1].w);
            *(ushort8_t*)&smem[pb + (q * 64 + srowA) * 64 + wAsh] = o;
        }
    };
    auto STAGE_B = [&](int T) {
        const int pb = (T % 3) * G1_BUF;
        #pragma unroll
        for (int q = 0; q < 3; ++q)
            gload_lds16(gB + (size_t)(q * 64) * HID + (size_t)T * 64,
                        &smem[pb + G1_BM * 64 + q * 4096 + tid * 8]);
    };

    // prologue: tiles 0,1 (A via regs, B via gload_lds)
    {
        float4 av0[2][2], av1[2][2];
        LOAD_A(0, av0); LOAD_A(1, av1);
        FENCE();
        STAGE_B(0); STAGE_B(1);
        WRITE_A(0, av0);    // compiler waits vmcnt(6): A0+A1 landed
        WRITE_A(1, av1);
        vmcnt_wait<3>();    // B(0) landed (B(1)'s 3 still in flight)
        LGKM0();
    }

    float4 av[2][2];
    for (int t = 0; t < G1_NT; ++t) {
        const int sb = (t % 3) * G1_BUF;
        BARF();   // the ONLY barrier per tile

        #pragma unroll
        for (int kk = 0; kk < 2; ++kk) {
            const int cxk = (((kk * 4 + fq) ^ frsw)) << 3;
            bf16x8_t aF[AF], bF[BF];
            #pragma unroll
            for (int mm = 0; mm < AF; ++mm)
                aF[mm] = *(const bf16x8_t*)&smem[sb + (wm*64 + mm*16 + fr)*64 + cxk];
            #pragma unroll
            for (int nn = 0; nn < BF; ++nn)
                bF[nn] = *(const bf16x8_t*)&smem[sb + G1_BM*64 + (wn*48 + nn*16 + fr)*64 + cxk];

            if (kk == 0 && t + 2 < G1_NT) {
                LOAD_A(t + 2, av);   // A loads issued first...
                FENCE();
                STAGE_B(t + 2);      // ...then B gloads (in-order vmcnt)
            }

            __builtin_amdgcn_s_setprio(1);
            #pragma unroll
            for (int mm = 0; mm < AF; ++mm)
                #pragma unroll
                for (int nn = 0; nn < BF; ++nn)
                    acc[mm][nn] = __builtin_amdgcn_mfma_f32_16x16x32_bf16(
                        aF[mm], bF[nn], acc[mm][nn], 0, 0, 0);
            __builtin_amdgcn_s_setprio(0);
        }

        if (t + 2 < G1_NT) {
            WRITE_A(t + 2, av);      // compiler waits A(t+2) => B(t+1) (older) landed too
        } else if (t + 1 < G1_NT) {
            vmcnt_wait<0>();         // drain B(NT-1)
        }
        LGKM0();                      // ds_writes visible before next barrier
    }

    // epilogue: bf16 out. C/D layout col=lane&15, row=(lane>>4)*4+reg
    const int crow = m0 + wm * 64 + fq * 4;
    const int ccol = n0 + wn * 48 + fr;
    #pragma unroll
    for (int m = 0; m < AF; m++)
        #pragma unroll
        for (int n = 0; n < BF; n++)
            #pragma unroll
            for (int rr = 0; rr < 4; rr++)
                C[(size_t)(crow + m*16 + rr) * QKV_N + ccol + n*16] = f2b(acc[m][n][rr]);
}

// ===========================================================================
// Single-barrier multi-buffered MFMA GEMM template (round-7 proven for G2).
// ===========================================================================
template <int BM, int BN, int BK, int NBUF, int NWM, int NWN, bool OBF16, typename OutT>
__global__ __launch_bounds__(512, 2)
void gemm_sb(const unsigned short* __restrict__ A,
             const unsigned short* __restrict__ Bt,
             OutT* __restrict__ C, int M, int N, int K) {
    constexpr int WM    = BM / NWM;
    constexpr int WN    = BN / NWN;
    constexpr int AF    = WM / 16;
    constexpr int BF    = WN / 16;
    constexpr int KK    = BK / 32;
    constexpr int BUF   = (BM + BN) * BK;
    constexpr int ROWS  = 4096 / BK;
    constexpr int AR    = BM / ROWS;
    constexpr int BR    = BN / ROWS;
    constexpr int RNDS  = AR + BR;
    constexpr int DEPTH = NBUF - 2;

    __shared__ unsigned short smem[NBUF * BUF];

    const int tid  = threadIdx.x;
    const int lane = tid & 63;
    const int wave = tid >> 6;
    const int wm   = wave / NWN;
    const int wn   = wave % NWN;
    const int fr   = lane & 15;
    const int fq   = lane >> 4;

    const int nbx = N / BN;
    int bid = blockIdx.x;
    const int cpx = gridDim.x >> 3;
    bid = (bid & 7) * cpx + (bid >> 3);
    const int bx = bid % nbx, by = bid / nbx;
    const int m0 = by * BM, n0 = bx * BN;

    const int srow = tid / (BK / 8);
    const int sch  = tid & (BK / 8 - 1);
    const int ssw  = (BK == 64) ? (srow & 7) : ((srow >> 1) & 3);
    const int scs  = (sch ^ ssw) << 3;
    const unsigned short* gA = A  + (size_t)(m0 + srow) * K + scs;
    const unsigned short* gB = Bt + (size_t)(n0 + srow) * K + scs;

    const int frsw = (BK == 64) ? (fr & 7) : ((fr >> 1) & 3);

    f32x4_t acc[AF][BF];
    #pragma unroll
    for (int m = 0; m < AF; m++)
        #pragma unroll
        for (int n = 0; n < BF; n++)
            acc[m][n] = (f32x4_t){0.f, 0.f, 0.f, 0.f};

    const int NT = K / BK;

    auto STAGE = [&](int T) {
        const int pb = (T % NBUF) * BUF;
        #pragma unroll
        for (int q = 0; q < AR; ++q)
            gload_lds16(gA + (size_t)(q * ROWS) * K + (size_t)T * BK,
                        &smem[pb + q * 4096 + tid * 8]);
        #pragma unroll
        for (int q = 0; q < BR; ++q)
            gload_lds16(gB + (size_t)(q * ROWS) * K + (size_t)T * BK,
                        &smem[pb + BM * BK + q * 4096 + tid * 8]);
    };

    #pragma unroll
    for (int pt = 0; pt < NBUF - 1; ++pt) STAGE(pt);
    vmcnt_wait<DEPTH * RNDS>();

    for (int t = 0; t < NT; ++t) {
        const int sb = (t % NBUF) * BUF;
        BARF();

        #pragma unroll
        for (int kk = 0; kk < KK; ++kk) {
            const int cxk = (((kk * 4 + fq) ^ frsw)) << 3;
            bf16x8_t aF[AF], bF[BF];
            #pragma unroll
            for (int mm = 0; mm < AF; ++mm)
                aF[mm] = *(const bf16x8_t*)&smem[sb + (wm*WM + mm*16 + fr)*BK + cxk];
            #pragma unroll
            for (int nn = 0; nn < BF; ++nn)
                bF[nn] = *(const bf16x8_t*)&smem[sb + BM*BK + (wn*WN + nn*16 + fr)*BK + cxk];

            if (kk == 0 && t + NBUF - 1 < NT) STAGE(t + NBUF - 1);

            __builtin_amdgcn_s_setprio(1);
            #pragma unroll
            for (int mm = 0; mm < AF; ++mm)
                #pragma unroll
                for (int nn = 0; nn < BF; ++nn)
                    acc[mm][nn] = __builtin_amdgcn_mfma_f32_16x16x32_bf16(
                        aF[mm], bF[nn], acc[mm][nn], 0, 0, 0);
            __builtin_amdgcn_s_setprio(0);
        }

        if constexpr (DEPTH == 2) {
            if (t + 3 < NT)      { vmcnt_wait<2 * RNDS>(); }
            else if (t + 2 < NT) { vmcnt_wait<RNDS>(); }
            else if (t + 1 < NT) { vmcnt_wait<0>(); }
        } else {
            if (t + 2 < NT)      { vmcnt_wait<RNDS>(); }
            else if (t + 1 < NT) { vmcnt_wait<0>(); }
        }
    }

    const int crow = m0 + wm * WM + fq * 4;
    const int ccol = n0 + wn * WN + fr;
    #pragma unroll
    for (int m = 0; m < AF; m++)
        #pragma unroll
        for (int n = 0; n < BF; n++)
            #pragma unroll
            for (int rr = 0; rr < 4; rr++) {
                const size_t idx = (size_t)(crow + m*16 + rr) * N + ccol + n*16;
                if constexpr (OBF16) C[idx] = (OutT)f2b(acc[m][n][rr]);
                else                 C[idx] = (OutT)acc[m][n][rr];
            }
}

// --------- fused RMSNorm + RoPE + 16-token block-diagonal attention --------
__global__ __launch_bounds__(64) void attn_fused(const unsigned short* __restrict__ qkv,
                                                 const float* __restrict__ cosb,
                                                 const float* __restrict__ sinb,
                                                 const float* __restrict__ qw,
                                                 const float* __restrict__ kw,
                                                 unsigned short* __restrict__ out) {
    const int h    = blockIdx.x & (NH - 1);
    const int blk  = (blockIdx.x >> 4) & 127;
    const int b    = blockIdx.x >> 11;
    const int pos0 = blk * 16;
    const int kvh  = h >> 2;

    const int lane = threadIdx.x;
    const int r    = lane >> 2;
    const int qp   = lane & 3;
    const int d0   = qp * 16;

    __shared__ float qs[16][65];
    __shared__ float ks[16][65];
    __shared__ float vs[16][65];
    __shared__ float ps[16][17];

    const size_t rowb = ((size_t)(b * L_SEQ + pos0 + r)) * NQKV;
    const unsigned short* qptr = qkv + (rowb + h) * HD + d0;
    const unsigned short* kptr = qkv + (rowb + NH + kvh) * HD + d0;
    const unsigned short* vptr = qkv + (rowb + NH + NKV + kvh) * HD + d0;
    const size_t csrow = ((size_t)(b * L_SEQ + pos0 + r)) * HD + d0;

    float q[16], k[16], v[16], cs[16], sn[16];
    {
        ushort8_t q0 = *(const ushort8_t*)&qptr[0], q1 = *(const ushort8_t*)&qptr[8];
        ushort8_t k0 = *(const ushort8_t*)&kptr[0], k1 = *(const ushort8_t*)&kptr[8];
        ushort8_t v0 = *(const ushort8_t*)&vptr[0], v1 = *(const ushort8_t*)&vptr[8];
        #pragma unroll
        for (int i = 0; i < 8; i++) {
            q[i] = b2f(q0[i]); q[i+8] = b2f(q1[i]);
            k[i] = b2f(k0[i]); k[i+8] = b2f(k1[i]);
            v[i] = b2f(v0[i]); v[i+8] = b2f(v1[i]);
        }
        #pragma unroll
        for (int i = 0; i < 16; i += 4) {
            *(float4*)&cs[i] = *(const float4*)&cosb[csrow + i];
            *(float4*)&sn[i] = *(const float4*)&sinb[csrow + i];
        }
    }

    float sq = 0.f, sk = 0.f;
    #pragma unroll
    for (int i = 0; i < 16; i++) { sq += q[i]*q[i]; sk += k[i]*k[i]; }
    sq += __shfl_xor(sq, 1); sq += __shfl_xor(sq, 2);
    sk += __shfl_xor(sk, 1); sk += __shfl_xor(sk, 2);
    const float rq = rsqrtf(sq * (1.f / HD) + EPSV);
    const float rk = rsqrtf(sk * (1.f / HD) + EPSV);

    const float sgn = (qp < 2) ? -1.f : 1.f;
    #pragma unroll
    for (int i = 0; i < 16; i++) {
        float qn = q[i] * rq * qw[d0 + i];
        float kn = k[i] * rk * kw[d0 + i];
        float qo = __shfl_xor(qn, 2);
        float ko = __shfl_xor(kn, 2);
        qs[r][d0 + i] = qn * cs[i] + sgn * qo * sn[i];
        ks[r][d0 + i] = kn * cs[i] + sgn * ko * sn[i];
        vs[r][d0 + i] = v[i];
    }
    __syncthreads();

    float sc[4] = {0.f, 0.f, 0.f, 0.f};
    for (int d = 0; d < 64; d++) {
        const float qd = qs[r][d];
        sc[0] += qd * ks[qp     ][d];
        sc[1] += qd * ks[qp +  4][d];
        sc[2] += qd * ks[qp +  8][d];
        sc[3] += qd * ks[qp + 12][d];
    }
    #pragma unroll
    for (int cc = 0; cc < 4; cc++) {
        const int c = qp + cc * 4;
        sc[cc] = (c <= r) ? sc[cc] * 0.125f : -3.0e38f;
    }
    float mx = fmaxf(fmaxf(sc[0], sc[1]), fmaxf(sc[2], sc[3]));
    mx = fmaxf(mx, __shfl_xor(mx, 1));
    mx = fmaxf(mx, __shfl_xor(mx, 2));
    float e[4], sum = 0.f;
    #pragma unroll
    for (int cc = 0; cc < 4; cc++) { e[cc] = __expf(sc[cc] - mx); sum += e[cc]; }
    sum += __shfl_xor(sum, 1); sum += __shfl_xor(sum, 2);
    const float inv = 1.f / sum;
    #pragma unroll
    for (int cc = 0; cc < 4; cc++) ps[r][qp + cc * 4] = e[cc] * inv;
    __syncthreads();

    float o[16];
    #pragma unroll
    for (int i = 0; i < 16; i++) o[i] = 0.f;
    #pragma unroll
    for (int c = 0; c < 16; c++) {
        const float p = ps[r][c];
        #pragma unroll
        for (int i = 0; i < 16; i++) o[i] += p * vs[c][d0 + i];
    }

    __attribute__((aligned(16))) unsigned short ob[16];
    #pragma unroll
    for (int i = 0; i < 16; i++) ob[i] = f2b(o[i]);
    unsigned short* optr = out + (((size_t)(b * L_SEQ + pos0 + r) * NH + h) * HD) + d0;
    *(uint4*)optr       = *(uint4*)&ob[0];
    *((uint4*)optr + 1) = *(uint4*)&ob[8];
}

// ---------------------------------------------------------------------------
extern "C" void kernel_launch(void* const* d_in, const int* in_sizes, int n_in,
                              void* d_out, int out_size, void* d_ws, size_t ws_size,
                              hipStream_t stream) {
    const float* hid  = (const float*)d_in[0];
    const float* cosb = (const float*)d_in[2];
    const float* sinb = (const float*)d_in[3];
    const float* Wqkv = (const float*)d_in[4];
    const float* Wo   = (const float*)d_in[5];
    const float* qw   = (const float*)d_in[6];
    const float* kw   = (const float*)d_in[7];
    float* outp = (float*)d_out;

    char* ws = (char*)d_ws;
    unsigned short* WqkvT = (unsigned short*)ws; ws += (size_t)QKV_N * HID * 2;
    unsigned short* WoT   = (unsigned short*)ws; ws += (size_t)HID * O_N * 2;
    unsigned short* qkvb  = (unsigned short*)ws; ws += (size_t)M_ROWS * QKV_N * 2;
    unsigned short* attnb = (unsigned short*)ws;

    // merged weight transposes (Wqkv: 6144 blocks, Wo: 4096 blocks)
    transpose_both<<<dim3(6144 + 4096), 256, 0, stream>>>(Wqkv, WqkvT, Wo, WoT);

    // GEMM1 with fused fp32->bf16 A conversion (cvt kernel eliminated):
    //   qkv = H @ Wqkv (4096 x 1536 x 4096), 128x192/BK64/NBUF3, 256 blocks
    gemm1_f32a<<<dim3((M_ROWS / 128) * (QKV_N / 192)), 512, 0, stream>>>
        (hid, WqkvT, qkvb);

    // fused rmsnorm + rope + block-diag attention (bf16 in/out)
    attn_fused<<<dim3(B_SZ * (L_SEQ / 16) * NH), 64, 0, stream>>>(qkvb, cosb, sinb, qw, kw, attnb);

    // GEMM2 (revert to round-7 measured-best): out = attn @ Wo (4096x4096x1024)
    //   256x256 tiles, BK=32, NBUF=4 (128KB), 256 blocks (1/CU), 2Mx4N waves
    gemm_sb<256, 256, 32, 4, 2, 4, false, float>
        <<<dim3((M_ROWS / 256) * (HID / 256)), 512, 0, stream>>>
        (attnb, WoT, outp, M_ROWS, HID, O_N);
}

// Round 11
// 145.813 us; speedup vs baseline: 1.0450x; 1.0158x over previous
//
#include <hip/hip_runtime.h>
#include <hip/hip_bf16.h>
#include <cstdint>

// Problem constants (from reference)
#define B_SZ   2
#define L_SEQ  2048
#define HID    4096
#define NH     16
#define NKV    4
#define HD     64
#define NQKV   (NH + 2*NKV)      // 24
#define QKV_N  (NQKV*HD)         // 1536
#define O_N    (NH*HD)           // 1024
#define M_ROWS (B_SZ*L_SEQ)      // 4096
#define EPSV   1e-6f

typedef __bf16  bf16x8_t  __attribute__((ext_vector_type(8)));
typedef float   f32x4_t   __attribute__((ext_vector_type(4)));
typedef unsigned short ushort8_t __attribute__((ext_vector_type(8)));

__device__ __forceinline__ unsigned short f2b(float f) {
    union { float f; uint32_t u; } v; v.f = f;
    uint32_t r = v.u + 0x7FFFu + ((v.u >> 16) & 1u);   // RNE to bf16
    return (unsigned short)(r >> 16);
}
__device__ __forceinline__ float b2f(unsigned short u) {
    union { uint32_t u; float f; } v; v.u = ((uint32_t)u) << 16;
    return v.f;
}

__device__ __forceinline__ void gload_lds16(const void* g, void* l) {
    __builtin_amdgcn_global_load_lds(
        (__attribute__((address_space(1))) void*)(g),
        (__attribute__((address_space(3))) void*)(l),
        16, 0, 0);
}

#define BARF() do { asm volatile("" ::: "memory"); \
                    __builtin_amdgcn_s_barrier();  \
                    asm volatile("" ::: "memory"); } while (0)

template <int N> __device__ __forceinline__ void vmcnt_wait() {
    if constexpr (N == 4)       asm volatile("s_waitcnt vmcnt(4)"  ::: "memory");
    else if constexpr (N == 5)  asm volatile("s_waitcnt vmcnt(5)"  ::: "memory");
    else if constexpr (N == 6)  asm volatile("s_waitcnt vmcnt(6)"  ::: "memory");
    else if constexpr (N == 8)  asm volatile("s_waitcnt vmcnt(8)"  ::: "memory");
    else if constexpr (N == 12) asm volatile("s_waitcnt vmcnt(12)" ::: "memory");
    else                        asm volatile("s_waitcnt vmcnt(0)"  ::: "memory");
}

// ---------------- fp32 -> bf16 elementwise (8 elems/thread) ----------------
__global__ __launch_bounds__(256) void cvt_f32_bf16(const float* __restrict__ in,
                                                    unsigned short* __restrict__ out,
                                                    int n8) {
    int i = blockIdx.x * 256 + threadIdx.x;
    if (i >= n8) return;
    const float4* p = (const float4*)(in + (size_t)i * 8);
    float4 a = p[0], b = p[1];
    ushort8_t o;
    o[0]=f2b(a.x); o[1]=f2b(a.y); o[2]=f2b(a.z); o[3]=f2b(a.w);
    o[4]=f2b(b.x); o[5]=f2b(b.y); o[6]=f2b(b.z); o[7]=f2b(b.w);
    *(ushort8_t*)(out + (size_t)i * 8) = o;
}

// ---- merged weight transposes: fp32 (R x C) -> bf16 (C x R), both weights --
__global__ __launch_bounds__(256) void transpose_both(const float* __restrict__ Wqkv,
                                                      unsigned short* __restrict__ WqkvT,
                                                      const float* __restrict__ Wo,
                                                      unsigned short* __restrict__ WoT) {
    __shared__ float t[32][33];
    const float* in;
    unsigned short* out;
    int R, C, bx, by;
    if (blockIdx.x < 6144) {
        in = Wqkv; out = WqkvT; R = HID; C = QKV_N;
        bx = blockIdx.x % 48; by = blockIdx.x / 48;
    } else {
        int b = blockIdx.x - 6144;
        in = Wo; out = WoT; R = O_N; C = HID;
        bx = b % 128; by = b / 128;
    }
    const int c0 = bx * 32;
    const int r0 = by * 32;
    const int tx = threadIdx.x & 31;
    const int ty = threadIdx.x >> 5;
    #pragma unroll
    for (int i = 0; i < 32; i += 8)
        t[ty + i][tx] = in[(size_t)(r0 + ty + i) * C + c0 + tx];
    __syncthreads();
    #pragma unroll
    for (int i = 0; i < 32; i += 8)
        out[(size_t)(c0 + ty + i) * R + r0 + tx] = f2b(t[tx][ty + i]);
}

// ===========================================================================
// Single-barrier multi-buffered MFMA GEMM template (round-6/7 proven).
//   C[M,N] = A[M,K] * Bt[N,K]^T, bf16 in, OutT out.
//   8 waves as NWM x NWN, per-wave WM x WN, one barrier + one counted vmcnt
//   per K-tile. NBUF LDS buffers; stage(t+NBUF-1) issued during tile t.
//   Hazard proof: stage(t) targets buf[(t+NBUF-1)%NBUF], never read during
//   tiles t..t+NBUF-2; a wave passes barrier(t+1) only after its tile-t
//   ds_reads completed (lgkm before its MFMAs). In-order vmcnt: at end of
//   tile t, wait<(NBUF-2)*RNDS> retires all but the newest NBUF-2 stage
//   groups => tile t+1 fully landed.
//   T2 swizzle (both-sides involution): BK=64 -> chunk^(row&7) on 128B rows;
//   BK=32 -> chunk^((row>>1)&3) on 64B rows.
// ===========================================================================
template <int BM, int BN, int BK, int NBUF, int NWM, int NWN, bool OBF16, typename OutT>
__global__ __launch_bounds__(512, 2)
void gemm_sb(const unsigned short* __restrict__ A,
             const unsigned short* __restrict__ Bt,
             OutT* __restrict__ C, int M, int N, int K) {
    constexpr int WM    = BM / NWM;
    constexpr int WN    = BN / NWN;
    constexpr int AF    = WM / 16;
    constexpr int BF    = WN / 16;
    constexpr int KK    = BK / 32;
    constexpr int BUF   = (BM + BN) * BK;
    constexpr int ROWS  = 4096 / BK;
    constexpr int AR    = BM / ROWS;
    constexpr int BR    = BN / ROWS;
    constexpr int RNDS  = AR + BR;
    constexpr int DEPTH = NBUF - 2;

    __shared__ unsigned short smem[NBUF * BUF];

    const int tid  = threadIdx.x;
    const int lane = tid & 63;
    const int wave = tid >> 6;
    const int wm   = wave / NWN;
    const int wn   = wave % NWN;
    const int fr   = lane & 15;
    const int fq   = lane >> 4;

    const int nbx = N / BN;
    int bid = blockIdx.x;
    const int cpx = gridDim.x >> 3;
    bid = (bid & 7) * cpx + (bid >> 3);
    const int bx = bid % nbx, by = bid / nbx;
    const int m0 = by * BM, n0 = bx * BN;

    const int srow = tid / (BK / 8);
    const int sch  = tid & (BK / 8 - 1);
    const int ssw  = (BK == 64) ? (srow & 7) : ((srow >> 1) & 3);
    const int scs  = (sch ^ ssw) << 3;
    const unsigned short* gA = A  + (size_t)(m0 + srow) * K + scs;
    const unsigned short* gB = Bt + (size_t)(n0 + srow) * K + scs;

    const int frsw = (BK == 64) ? (fr & 7) : ((fr >> 1) & 3);

    f32x4_t acc[AF][BF];
    #pragma unroll
    for (int m = 0; m < AF; m++)
        #pragma unroll
        for (int n = 0; n < BF; n++)
            acc[m][n] = (f32x4_t){0.f, 0.f, 0.f, 0.f};

    const int NT = K / BK;

    auto STAGE = [&](int T) {
        const int pb = (T % NBUF) * BUF;
        #pragma unroll
        for (int q = 0; q < AR; ++q)
            gload_lds16(gA + (size_t)(q * ROWS) * K + (size_t)T * BK,
                        &smem[pb + q * 4096 + tid * 8]);
        #pragma unroll
        for (int q = 0; q < BR; ++q)
            gload_lds16(gB + (size_t)(q * ROWS) * K + (size_t)T * BK,
                        &smem[pb + BM * BK + q * 4096 + tid * 8]);
    };

    #pragma unroll
    for (int pt = 0; pt < NBUF - 1; ++pt) STAGE(pt);
    vmcnt_wait<DEPTH * RNDS>();

    for (int t = 0; t < NT; ++t) {
        const int sb = (t % NBUF) * BUF;
        BARF();   // the ONLY barrier per tile

        #pragma unroll
        for (int kk = 0; kk < KK; ++kk) {
            const int cxk = (((kk * 4 + fq) ^ frsw)) << 3;
            bf16x8_t aF[AF], bF[BF];
            #pragma unroll
            for (int mm = 0; mm < AF; ++mm)
                aF[mm] = *(const bf16x8_t*)&smem[sb + (wm*WM + mm*16 + fr)*BK + cxk];
            #pragma unroll
            for (int nn = 0; nn < BF; ++nn)
                bF[nn] = *(const bf16x8_t*)&smem[sb + BM*BK + (wn*WN + nn*16 + fr)*BK + cxk];

            if (kk == 0 && t + NBUF - 1 < NT) STAGE(t + NBUF - 1);

            __builtin_amdgcn_s_setprio(1);
            #pragma unroll
            for (int mm = 0; mm < AF; ++mm)
                #pragma unroll
                for (int nn = 0; nn < BF; ++nn)
                    acc[mm][nn] = __builtin_amdgcn_mfma_f32_16x16x32_bf16(
                        aF[mm], bF[nn], acc[mm][nn], 0, 0, 0);
            __builtin_amdgcn_s_setprio(0);
        }

        if constexpr (DEPTH == 2) {
            if (t + 3 < NT)      { vmcnt_wait<2 * RNDS>(); }
            else if (t + 2 < NT) { vmcnt_wait<RNDS>(); }
            else if (t + 1 < NT) { vmcnt_wait<0>(); }
        } else {
            if (t + 2 < NT)      { vmcnt_wait<RNDS>(); }
            else if (t + 1 < NT) { vmcnt_wait<0>(); }
        }
    }

    // C/D layout (m89-verified): col = lane&15, row = (lane>>4)*4 + reg
    const int crow = m0 + wm * WM + fq * 4;
    const int ccol = n0 + wn * WN + fr;
    #pragma unroll
    for (int m = 0; m < AF; m++)
        #pragma unroll
        for (int n = 0; n < BF; n++)
            #pragma unroll
            for (int rr = 0; rr < 4; rr++) {
                const size_t idx = (size_t)(crow + m*16 + rr) * N + ccol + n*16;
                if constexpr (OBF16) C[idx] = (OutT)f2b(acc[m][n][rr]);
                else                 C[idx] = (OutT)acc[m][n][rr];
            }
}

// --------- fused RMSNorm + RoPE + 16-token block-diagonal attention --------
__global__ __launch_bounds__(64) void attn_fused(const unsigned short* __restrict__ qkv,
                                                 const float* __restrict__ cosb,
                                                 const float* __restrict__ sinb,
                                                 const float* __restrict__ qw,
                                                 const float* __restrict__ kw,
                                                 unsigned short* __restrict__ out) {
    const int h    = blockIdx.x & (NH - 1);
    const int blk  = (blockIdx.x >> 4) & 127;
    const int b    = blockIdx.x >> 11;
    const int pos0 = blk * 16;
    const int kvh  = h >> 2;

    const int lane = threadIdx.x;
    const int r    = lane >> 2;
    const int qp   = lane & 3;
    const int d0   = qp * 16;

    __shared__ float qs[16][65];
    __shared__ float ks[16][65];
    __shared__ float vs[16][65];
    __shared__ float ps[16][17];

    const size_t rowb = ((size_t)(b * L_SEQ + pos0 + r)) * NQKV;
    const unsigned short* qptr = qkv + (rowb + h) * HD + d0;
    const unsigned short* kptr = qkv + (rowb + NH + kvh) * HD + d0;
    const unsigned short* vptr = qkv + (rowb + NH + NKV + kvh) * HD + d0;
    const size_t csrow = ((size_t)(b * L_SEQ + pos0 + r)) * HD + d0;

    float q[16], k[16], v[16], cs[16], sn[16];
    {
        ushort8_t q0 = *(const ushort8_t*)&qptr[0], q1 = *(const ushort8_t*)&qptr[8];
        ushort8_t k0 = *(const ushort8_t*)&kptr[0], k1 = *(const ushort8_t*)&kptr[8];
        ushort8_t v0 = *(const ushort8_t*)&vptr[0], v1 = *(const ushort8_t*)&vptr[8];
        #pragma unroll
        for (int i = 0; i < 8; i++) {
            q[i] = b2f(q0[i]); q[i+8] = b2f(q1[i]);
            k[i] = b2f(k0[i]); k[i+8] = b2f(k1[i]);
            v[i] = b2f(v0[i]); v[i+8] = b2f(v1[i]);
        }
        #pragma unroll
        for (int i = 0; i < 16; i += 4) {
            *(float4*)&cs[i] = *(const float4*)&cosb[csrow + i];
            *(float4*)&sn[i] = *(const float4*)&sinb[csrow + i];
        }
    }

    float sq = 0.f, sk = 0.f;
    #pragma unroll
    for (int i = 0; i < 16; i++) { sq += q[i]*q[i]; sk += k[i]*k[i]; }
    sq += __shfl_xor(sq, 1); sq += __shfl_xor(sq, 2);
    sk += __shfl_xor(sk, 1); sk += __shfl_xor(sk, 2);
    const float rq = rsqrtf(sq * (1.f / HD) + EPSV);
    const float rk = rsqrtf(sk * (1.f / HD) + EPSV);

    const float sgn = (qp < 2) ? -1.f : 1.f;
    #pragma unroll
    for (int i = 0; i < 16; i++) {
        float qn = q[i] * rq * qw[d0 + i];
        float kn = k[i] * rk * kw[d0 + i];
        float qo = __shfl_xor(qn, 2);
        float ko = __shfl_xor(kn, 2);
        qs[r][d0 + i] = qn * cs[i] + sgn * qo * sn[i];
        ks[r][d0 + i] = kn * cs[i] + sgn * ko * sn[i];
        vs[r][d0 + i] = v[i];
    }
    __syncthreads();

    float sc[4] = {0.f, 0.f, 0.f, 0.f};
    for (int d = 0; d < 64; d++) {
        const float qd = qs[r][d];
        sc[0] += qd * ks[qp     ][d];
        sc[1] += qd * ks[qp +  4][d];
        sc[2] += qd * ks[qp +  8][d];
        sc[3] += qd * ks[qp + 12][d];
    }
    #pragma unroll
    for (int cc = 0; cc < 4; cc++) {
        const int c = qp + cc * 4;
        sc[cc] = (c <= r) ? sc[cc] * 0.125f : -3.0e38f;
    }
    float mx = fmaxf(fmaxf(sc[0], sc[1]), fmaxf(sc[2], sc[3]));
    mx = fmaxf(mx, __shfl_xor(mx, 1));
    mx = fmaxf(mx, __shfl_xor(mx, 2));
    float e[4], sum = 0.f;
    #pragma unroll
    for (int cc = 0; cc < 4; cc++) { e[cc] = __expf(sc[cc] - mx); sum += e[cc]; }
    sum += __shfl_xor(sum, 1); sum += __shfl_xor(sum, 2);
    const float inv = 1.f / sum;
    #pragma unroll
    for (int cc = 0; cc < 4; cc++) ps[r][qp + cc * 4] = e[cc] * inv;
    __syncthreads();

    float o[16];
    #pragma unroll
    for (int i = 0; i < 16; i++) o[i] = 0.f;
    #pragma unroll
    for (int c = 0; c < 16; c++) {
        const float p = ps[r][c];
        #pragma unroll
        for (int i = 0; i < 16; i++) o[i] += p * vs[c][d0 + i];
    }

    __attribute__((aligned(16))) unsigned short ob[16];
    #pragma unroll
    for (int i = 0; i < 16; i++) ob[i] = f2b(o[i]);
    unsigned short* optr = out + (((size_t)(b * L_SEQ + pos0 + r) * NH + h) * HD) + d0;
    *(uint4*)optr       = *(uint4*)&ob[0];
    *((uint4*)optr + 1) = *(uint4*)&ob[8];
}

// ---------------------------------------------------------------------------
extern "C" void kernel_launch(void* const* d_in, const int* in_sizes, int n_in,
                              void* d_out, int out_size, void* d_ws, size_t ws_size,
                              hipStream_t stream) {
    const float* hid  = (const float*)d_in[0];
    const float* cosb = (const float*)d_in[2];
    const float* sinb = (const float*)d_in[3];
    const float* Wqkv = (const float*)d_in[4];
    const float* Wo   = (const float*)d_in[5];
    const float* qw   = (const float*)d_in[6];
    const float* kw   = (const float*)d_in[7];
    float* outp = (float*)d_out;

    char* ws = (char*)d_ws;
    unsigned short* Hb    = (unsigned short*)ws; ws += (size_t)M_ROWS * HID * 2;
    unsigned short* WqkvT = (unsigned short*)ws; ws += (size_t)QKV_N * HID * 2;
    unsigned short* WoT   = (unsigned short*)ws; ws += (size_t)HID * O_N * 2;
    unsigned short* qkvb  = (unsigned short*)ws; ws += (size_t)M_ROWS * QKV_N * 2;
    unsigned short* attnb = (unsigned short*)ws;

    // fp32 -> bf16 for hidden states (reverted: fused-A was a 42us stall)
    {
        int n8 = (M_ROWS * HID) / 8;
        cvt_f32_bf16<<<(n8 + 255) / 256, 256, 0, stream>>>(hid, Hb, n8);
    }
    // merged weight transposes (Wqkv: 6144 blocks, Wo: 4096 blocks)
    transpose_both<<<dim3(6144 + 4096), 256, 0, stream>>>(Wqkv, WqkvT, Wo, WoT);

    // GEMM1 (round-6 measured best): qkv = H @ Wqkv (4096 x 1536 x 4096)
    //   128x192 tiles, BK=64, NBUF=3 (120KB), 256 blocks (full coverage),
    //   2Mx4N waves, per-kk reads, single barrier + vmcnt(5)/tile
    gemm_sb<128, 192, 64, 3, 2, 4, true, unsigned short>
        <<<dim3((M_ROWS / 128) * (QKV_N / 192)), 512, 0, stream>>>
        (Hb, WqkvT, qkvb, M_ROWS, QKV_N, HID);

    // fused rmsnorm + rope + block-diag attention (bf16 in/out)
    attn_fused<<<dim3(B_SZ * (L_SEQ / 16) * NH), 64, 0, stream>>>(qkvb, cosb, sinb, qw, kw, attnb);

    // GEMM2 (round-7/10 measured best): out = attn @ Wo (4096 x 4096 x 1024)
    //   256x256 tiles, BK=32, NBUF=4 (128KB), 256 blocks (1/CU), 2Mx4N waves
    gemm_sb<256, 256, 32, 4, 2, 4, false, float>
        <<<dim3((M_ROWS / 256) * (HID / 256)), 512, 0, stream>>>
        (attnb, WoT, outp, M_ROWS, HID, O_N);
}

// Round 12
// 144.475 us; speedup vs baseline: 1.0547x; 1.0093x over previous
//
#include <hip/hip_runtime.h>
#include <hip/hip_bf16.h>
#include <cstdint>

// Problem constants (from reference)
#define B_SZ   2
#define L_SEQ  2048
#define HID    4096
#define NH     16
#define NKV    4
#define HD     64
#define NQKV   (NH + 2*NKV)      // 24
#define QKV_N  (NQKV*HD)         // 1536
#define O_N    (NH*HD)           // 1024
#define M_ROWS (B_SZ*L_SEQ)      // 4096
#define EPSV   1e-6f

typedef __bf16  bf16x8_t  __attribute__((ext_vector_type(8)));
typedef float   f32x4_t   __attribute__((ext_vector_type(4)));
typedef unsigned short ushort8_t __attribute__((ext_vector_type(8)));

__device__ __forceinline__ unsigned short f2b(float f) {
    union { float f; uint32_t u; } v; v.f = f;
    uint32_t r = v.u + 0x7FFFu + ((v.u >> 16) & 1u);   // RNE to bf16
    return (unsigned short)(r >> 16);
}
__device__ __forceinline__ float b2f(unsigned short u) {
    union { uint32_t u; float f; } v; v.u = ((uint32_t)u) << 16;
    return v.f;
}

__device__ __forceinline__ void gload_lds16(const void* g, void* l) {
    __builtin_amdgcn_global_load_lds(
        (__attribute__((address_space(1))) void*)(g),
        (__attribute__((address_space(3))) void*)(l),
        16, 0, 0);
}

#define BARF() do { asm volatile("" ::: "memory"); \
                    __builtin_amdgcn_s_barrier();  \
                    asm volatile("" ::: "memory"); } while (0)
#define LGKMW() asm volatile("s_waitcnt lgkmcnt(0)" ::: "memory")

template <int N> __device__ __forceinline__ void vmcnt_wait() {
    if constexpr (N == 4)       asm volatile("s_waitcnt vmcnt(4)"  ::: "memory");
    else if constexpr (N == 5)  asm volatile("s_waitcnt vmcnt(5)"  ::: "memory");
    else if constexpr (N == 6)  asm volatile("s_waitcnt vmcnt(6)"  ::: "memory");
    else if constexpr (N == 8)  asm volatile("s_waitcnt vmcnt(8)"  ::: "memory");
    else if constexpr (N == 12) asm volatile("s_waitcnt vmcnt(12)" ::: "memory");
    else                        asm volatile("s_waitcnt vmcnt(0)"  ::: "memory");
}

// ---------------- fp32 -> bf16 elementwise (8 elems/thread) ----------------
__global__ __launch_bounds__(256) void cvt_f32_bf16(const float* __restrict__ in,
                                                    unsigned short* __restrict__ out,
                                                    int n8) {
    int i = blockIdx.x * 256 + threadIdx.x;
    if (i >= n8) return;
    const float4* p = (const float4*)(in + (size_t)i * 8);
    float4 a = p[0], b = p[1];
    ushort8_t o;
    o[0]=f2b(a.x); o[1]=f2b(a.y); o[2]=f2b(a.z); o[3]=f2b(a.w);
    o[4]=f2b(b.x); o[5]=f2b(b.y); o[6]=f2b(b.z); o[7]=f2b(b.w);
    *(ushort8_t*)(out + (size_t)i * 8) = o;
}

// ---- merged weight transposes: fp32 (R x C) -> bf16 (C x R), both weights --
__global__ __launch_bounds__(256) void transpose_both(const float* __restrict__ Wqkv,
                                                      unsigned short* __restrict__ WqkvT,
                                                      const float* __restrict__ Wo,
                                                      unsigned short* __restrict__ WoT) {
    __shared__ float t[32][33];
    const float* in;
    unsigned short* out;
    int R, C, bx, by;
    if (blockIdx.x < 6144) {
        in = Wqkv; out = WqkvT; R = HID; C = QKV_N;
        bx = blockIdx.x % 48; by = blockIdx.x / 48;
    } else {
        int b = blockIdx.x - 6144;
        in = Wo; out = WoT; R = O_N; C = HID;
        bx = b % 128; by = b / 128;
    }
    const int c0 = bx * 32;
    const int r0 = by * 32;
    const int tx = threadIdx.x & 31;
    const int ty = threadIdx.x >> 5;
    #pragma unroll
    for (int i = 0; i < 32; i += 8)
        t[ty + i][tx] = in[(size_t)(r0 + ty + i) * C + c0 + tx];
    __syncthreads();
    #pragma unroll
    for (int i = 0; i < 32; i += 8)
        out[(size_t)(c0 + ty + i) * R + r0 + tx] = f2b(t[tx][ty + i]);
}

// ===========================================================================
// Single-barrier multi-buffered MFMA GEMM template (round-6 proven; G1 only).
// ===========================================================================
template <int BM, int BN, int BK, int NBUF, int NWM, int NWN, bool OBF16, typename OutT>
__global__ __launch_bounds__(512, 2)
void gemm_sb(const unsigned short* __restrict__ A,
             const unsigned short* __restrict__ Bt,
             OutT* __restrict__ C, int M, int N, int K) {
    constexpr int WM    = BM / NWM;
    constexpr int WN    = BN / NWN;
    constexpr int AF    = WM / 16;
    constexpr int BF    = WN / 16;
    constexpr int KK    = BK / 32;
    constexpr int BUF   = (BM + BN) * BK;
    constexpr int ROWS  = 4096 / BK;
    constexpr int AR    = BM / ROWS;
    constexpr int BR    = BN / ROWS;
    constexpr int RNDS  = AR + BR;
    constexpr int DEPTH = NBUF - 2;

    __shared__ unsigned short smem[NBUF * BUF];

    const int tid  = threadIdx.x;
    const int lane = tid & 63;
    const int wave = tid >> 6;
    const int wm   = wave / NWN;
    const int wn   = wave % NWN;
    const int fr   = lane & 15;
    const int fq   = lane >> 4;

    const int nbx = N / BN;
    int bid = blockIdx.x;
    const int cpx = gridDim.x >> 3;
    bid = (bid & 7) * cpx + (bid >> 3);
    const int bx = bid % nbx, by = bid / nbx;
    const int m0 = by * BM, n0 = bx * BN;

    const int srow = tid / (BK / 8);
    const int sch  = tid & (BK / 8 - 1);
    const int ssw  = (BK == 64) ? (srow & 7) : ((srow >> 1) & 3);
    const int scs  = (sch ^ ssw) << 3;
    const unsigned short* gA = A  + (size_t)(m0 + srow) * K + scs;
    const unsigned short* gB = Bt + (size_t)(n0 + srow) * K + scs;

    const int frsw = (BK == 64) ? (fr & 7) : ((fr >> 1) & 3);

    f32x4_t acc[AF][BF];
    #pragma unroll
    for (int m = 0; m < AF; m++)
        #pragma unroll
        for (int n = 0; n < BF; n++)
            acc[m][n] = (f32x4_t){0.f, 0.f, 0.f, 0.f};

    const int NT = K / BK;

    auto STAGE = [&](int T) {
        const int pb = (T % NBUF) * BUF;
        #pragma unroll
        for (int q = 0; q < AR; ++q)
            gload_lds16(gA + (size_t)(q * ROWS) * K + (size_t)T * BK,
                        &smem[pb + q * 4096 + tid * 8]);
        #pragma unroll
        for (int q = 0; q < BR; ++q)
            gload_lds16(gB + (size_t)(q * ROWS) * K + (size_t)T * BK,
                        &smem[pb + BM * BK + q * 4096 + tid * 8]);
    };

    #pragma unroll
    for (int pt = 0; pt < NBUF - 1; ++pt) STAGE(pt);
    vmcnt_wait<DEPTH * RNDS>();

    for (int t = 0; t < NT; ++t) {
        const int sb = (t % NBUF) * BUF;
        BARF();   // the ONLY barrier per tile

        #pragma unroll
        for (int kk = 0; kk < KK; ++kk) {
            const int cxk = (((kk * 4 + fq) ^ frsw)) << 3;
            bf16x8_t aF[AF], bF[BF];
            #pragma unroll
            for (int mm = 0; mm < AF; ++mm)
                aF[mm] = *(const bf16x8_t*)&smem[sb + (wm*WM + mm*16 + fr)*BK + cxk];
            #pragma unroll
            for (int nn = 0; nn < BF; ++nn)
                bF[nn] = *(const bf16x8_t*)&smem[sb + BM*BK + (wn*WN + nn*16 + fr)*BK + cxk];

            if (kk == 0 && t + NBUF - 1 < NT) STAGE(t + NBUF - 1);

            __builtin_amdgcn_s_setprio(1);
            #pragma unroll
            for (int mm = 0; mm < AF; ++mm)
                #pragma unroll
                for (int nn = 0; nn < BF; ++nn)
                    acc[mm][nn] = __builtin_amdgcn_mfma_f32_16x16x32_bf16(
                        aF[mm], bF[nn], acc[mm][nn], 0, 0, 0);
            __builtin_amdgcn_s_setprio(0);
        }

        if constexpr (DEPTH == 2) {
            if (t + 3 < NT)      { vmcnt_wait<2 * RNDS>(); }
            else if (t + 2 < NT) { vmcnt_wait<RNDS>(); }
            else if (t + 1 < NT) { vmcnt_wait<0>(); }
        } else {
            if (t + 2 < NT)      { vmcnt_wait<RNDS>(); }
            else if (t + 1 < NT) { vmcnt_wait<0>(); }
        }
    }

    const int crow = m0 + wm * WM + fq * 4;
    const int ccol = n0 + wn * WN + fr;
    #pragma unroll
    for (int m = 0; m < AF; m++)
        #pragma unroll
        for (int n = 0; n < BF; n++)
            #pragma unroll
            for (int rr = 0; rr < 4; rr++) {
                const size_t idx = (size_t)(crow + m*16 + rr) * N + ccol + n*16;
                if constexpr (OBF16) C[idx] = (OutT)f2b(acc[m][n][rr]);
                else                 C[idx] = (OutT)acc[m][n][rr];
            }
}

// ===========================================================================
// GEMM2: m201-style 8-phase schedule.  out[4096,4096] = attnb @ WoT^T, K=1024.
//   256x256 tile, BK=64, grid 256 (1/CU), 8 waves 2Mx4N (per-wave 128x64,
//   AF=8 BF=4). 2 LDS buffers x 64KB (tile t in buf t&1); 2 K-tiles per
//   iteration, 8 phases. Each phase: {ds_read one (mh,kk) quadrant (4 A +
//   opt 4 B) | stage 2 quarter-gloads | BARF | lgkm0 | setprio(1) 16 MFMA
//   setprio(0) | BARF}. vmcnt(4) only at p4/p8.
//   Region-retire proof (per tile, quadrant order (0,k0),(0,k1),(1,k0),(1,k1)):
//     A quarters q0,q2 (rows 0-63,128-191) fully read at p2-end;
//     A q1,q3 at p4-end; ALL B quarters at p2-end (each wave reads its own
//     64 B-rows at kk0@p1, kk1@p2). Stage slots: p1:[t1 A q1,q3] p2:[t1 B
//     q2,q3] p3:[t0+2 A q0,q2] p4:[t0+2 B q0,q1] p5:[t0+2 A q1,q3]
//     p6:[t0+2 B q2,q3] p7:[t1+2 A q0,q2] p8:[t1+2 B q0,q1] — each write
//     targets a region whose reads retired >=1 barrier before the issue.
//   vmcnt(4)@p4 retires through p2 (tile t1 complete before p5 reads it);
//   vmcnt(4)@p8 retires through p6 (tile t0+2 complete before next-iter p1).
//   Last iteration: p4 -> vmcnt(0) (p3/p4 stages skipped, count would no-op).
// ===========================================================================
#define G2_BUF 32768   // shorts per buffer (64 KiB)

__global__ __launch_bounds__(512, 2)
void gemm2_8p(const unsigned short* __restrict__ A,
              const unsigned short* __restrict__ Bt,
              float* __restrict__ C) {
    constexpr int K     = O_N;        // 1024
    constexpr int N     = HID;        // 4096
    constexpr int NT    = K / 64;     // 16
    constexpr int NITER = NT / 2;     // 8

    __shared__ unsigned short smem[2 * G2_BUF];   // 128 KiB

    const int tid  = threadIdx.x;
    const int lane = tid & 63;
    const int wave = tid >> 6;
    const int wm   = wave >> 2;       // 0..1  (128 rows)
    const int wn   = wave & 3;        // 0..3  (64 cols)
    const int fr   = lane & 15;
    const int fq   = lane >> 4;

    const int nbx = N >> 8;           // 16
    int bid = blockIdx.x;
    const int cpx = gridDim.x >> 3;
    bid = (bid & 7) * cpx + (bid >> 3);
    const int bx = bid % nbx, by = bid / nbx;
    const int m0 = by << 8, n0 = bx << 8;

    const int srow = tid >> 3;
    const int scs  = ((tid & 7) ^ (srow & 7)) << 3;
    const unsigned short* gA = A  + (size_t)(m0 + srow) * K + scs;
    const unsigned short* gB = Bt + (size_t)(n0 + srow) * K + scs;
    const int frsw = fr & 7;

    f32x4_t acc[8][4];
    #pragma unroll
    for (int m = 0; m < 8; m++)
        #pragma unroll
        for (int n = 0; n < 4; n++)
            acc[m][n] = (f32x4_t){0.f, 0.f, 0.f, 0.f};

    // stage quarter q (64 rows) of tile T
#define SA(T, q) gload_lds16(gA + (size_t)((q)*64)*K + (size_t)(T)*64, \
                             &smem[((T)&1)*G2_BUF + (q)*4096 + tid*8])
#define SB(T, q) gload_lds16(gB + (size_t)((q)*64)*K + (size_t)(T)*64, \
                             &smem[((T)&1)*G2_BUF + 16384 + (q)*4096 + tid*8])
#define RDA(T, MH, KI) { _Pragma("unroll") for (int mm = 0; mm < 4; ++mm) { \
    const int ro = ((T)&1)*G2_BUF + (wm*128 + (MH)*64 + mm*16 + fr)*64; \
    aF[mm] = *(const bf16x8_t*)&smem[ro + ((((KI)*4 + fq) ^ frsw) << 3)]; } }
#define RDB(T, KI, dst) { _Pragma("unroll") for (int nn = 0; nn < 4; ++nn) { \
    const int ro = ((T)&1)*G2_BUF + 16384 + (wn*64 + nn*16 + fr)*64; \
    dst[nn] = *(const bf16x8_t*)&smem[ro + ((((KI)*4 + fq) ^ frsw) << 3)]; } }
#define MM16(MH, BS) { __builtin_amdgcn_s_setprio(1); \
    _Pragma("unroll") for (int mm = 0; mm < 4; ++mm) \
    _Pragma("unroll") for (int nn = 0; nn < 4; ++nn) \
        acc[(MH)*4 + mm][nn] = __builtin_amdgcn_mfma_f32_16x16x32_bf16( \
            aF[mm], BS[nn], acc[(MH)*4 + mm][nn], 0, 0, 0); \
    __builtin_amdgcn_s_setprio(0); }

    // prologue: tile0 full (8) + tile1 {A q0,q2; B q0,q1} (4)
    SA(0,0); SA(0,1); SA(0,2); SA(0,3);
    SB(0,0); SB(0,1); SB(0,2); SB(0,3);
    SA(1,0); SA(1,2); SB(1,0); SB(1,1);
    vmcnt_wait<4>();          // tile0 landed; tile1-part's 4 in flight
    BARF();

    for (int i = 0; i < NITER; ++i) {
        const int t0 = 2*i, t1 = 2*i + 1;
        bf16x8_t aF[4], b0[4], b1[4];

        // p1: (t0, mh0, kk0) + B(kk0); stage t1 A q1,q3
        RDA(t0, 0, 0); RDB(t0, 0, b0);
        SA(t1, 1); SA(t1, 3);
        BARF(); LGKMW(); MM16(0, b0); BARF();
        // p2: (t0, mh0, kk1) + B(kk1); stage t1 B q2,q3
        RDA(t0, 0, 1); RDB(t0, 1, b1);
        SB(t1, 2); SB(t1, 3);
        BARF(); LGKMW(); MM16(0, b1); BARF();
        // p3: (t0, mh1, kk0); stage t0+2 A q0,q2
        RDA(t0, 1, 0);
        if (t0 + 2 < NT) { SA(t0 + 2, 0); SA(t0 + 2, 2); }
        BARF(); LGKMW(); MM16(1, b0); BARF();
        // p4: (t0, mh1, kk1); stage t0+2 B q0,q1; gate tile t1
        RDA(t0, 1, 1);
        if (t0 + 2 < NT) { SB(t0 + 2, 0); SB(t0 + 2, 1); }
        BARF(); LGKMW(); MM16(1, b1);
        if (i + 1 < NITER) { vmcnt_wait<4>(); } else { vmcnt_wait<0>(); }
        BARF();
        // p5: (t1, mh0, kk0) + B(kk0); stage t0+2 A q1,q3
        RDA(t1, 0, 0); RDB(t1, 0, b0);
        if (t0 + 2 < NT) { SA(t0 + 2, 1); SA(t0 + 2, 3); }
        BARF(); LGKMW(); MM16(0, b0); BARF();
        // p6: (t1, mh0, kk1) + B(kk1); stage t0+2 B q2,q3
        RDA(t1, 0, 1); RDB(t1, 1, b1);
        if (t0 + 2 < NT) { SB(t0 + 2, 2); SB(t0 + 2, 3); }
        BARF(); LGKMW(); MM16(0, b1); BARF();
        // p7: (t1, mh1, kk0); stage t1+2 A q0,q2
        RDA(t1, 1, 0);
        if (t1 + 2 < NT) { SA(t1 + 2, 0); SA(t1 + 2, 2); }
        BARF(); LGKMW(); MM16(1, b0); BARF();
        // p8: (t1, mh1, kk1); stage t1+2 B q0,q1; gate tile t0+2
        RDA(t1, 1, 1);
        if (t1 + 2 < NT) { SB(t1 + 2, 0); SB(t1 + 2, 1); }
        BARF(); LGKMW(); MM16(1, b1);
        if (i + 1 < NITER) { vmcnt_wait<4>(); }
        BARF();
    }
#undef SA
#undef SB
#undef RDA
#undef RDB
#undef MM16

    // epilogue: C/D layout col=lane&15, row=(lane>>4)*4+reg
    const int crow = m0 + wm * 128 + fq * 4;
    const int ccol = n0 + wn * 64 + fr;
    #pragma unroll
    for (int m = 0; m < 8; m++)
        #pragma unroll
        for (int n = 0; n < 4; n++)
            #pragma unroll
            for (int rr = 0; rr < 4; rr++)
                C[(size_t)(crow + m*16 + rr) * N + ccol + n*16] = acc[m][n][rr];
}

// --------- fused RMSNorm + RoPE + 16-token block-diagonal attention --------
__global__ __launch_bounds__(64) void attn_fused(const unsigned short* __restrict__ qkv,
                                                 const float* __restrict__ cosb,
                                                 const float* __restrict__ sinb,
                                                 const float* __restrict__ qw,
                                                 const float* __restrict__ kw,
                                                 unsigned short* __restrict__ out) {
    const int h    = blockIdx.x & (NH - 1);
    const int blk  = (blockIdx.x >> 4) & 127;
    const int b    = blockIdx.x >> 11;
    const int pos0 = blk * 16;
    const int kvh  = h >> 2;

    const int lane = threadIdx.x;
    const int r    = lane >> 2;
    const int qp   = lane & 3;
    const int d0   = qp * 16;

    __shared__ float qs[16][65];
    __shared__ float ks[16][65];
    __shared__ float vs[16][65];
    __shared__ float ps[16][17];

    const size_t rowb = ((size_t)(b * L_SEQ + pos0 + r)) * NQKV;
    const unsigned short* qptr = qkv + (rowb + h) * HD + d0;
    const unsigned short* kptr = qkv + (rowb + NH + kvh) * HD + d0;
    const unsigned short* vptr = qkv + (rowb + NH + NKV + kvh) * HD + d0;
    const size_t csrow = ((size_t)(b * L_SEQ + pos0 + r)) * HD + d0;

    float q[16], k[16], v[16], cs[16], sn[16];
    {
        ushort8_t q0 = *(const ushort8_t*)&qptr[0], q1 = *(const ushort8_t*)&qptr[8];
        ushort8_t k0 = *(const ushort8_t*)&kptr[0], k1 = *(const ushort8_t*)&kptr[8];
        ushort8_t v0 = *(const ushort8_t*)&vptr[0], v1 = *(const ushort8_t*)&vptr[8];
        #pragma unroll
        for (int i = 0; i < 8; i++) {
            q[i] = b2f(q0[i]); q[i+8] = b2f(q1[i]);
            k[i] = b2f(k0[i]); k[i+8] = b2f(k1[i]);
            v[i] = b2f(v0[i]); v[i+8] = b2f(v1[i]);
        }
        #pragma unroll
        for (int i = 0; i < 16; i += 4) {
            *(float4*)&cs[i] = *(const float4*)&cosb[csrow + i];
            *(float4*)&sn[i] = *(const float4*)&sinb[csrow + i];
        }
    }

    float sq = 0.f, sk = 0.f;
    #pragma unroll
    for (int i = 0; i < 16; i++) { sq += q[i]*q[i]; sk += k[i]*k[i]; }
    sq += __shfl_xor(sq, 1); sq += __shfl_xor(sq, 2);
    sk += __shfl_xor(sk, 1); sk += __shfl_xor(sk, 2);
    const float rq = rsqrtf(sq * (1.f / HD) + EPSV);
    const float rk = rsqrtf(sk * (1.f / HD) + EPSV);

    const float sgn = (qp < 2) ? -1.f : 1.f;
    #pragma unroll
    for (int i = 0; i < 16; i++) {
        float qn = q[i] * rq * qw[d0 + i];
        float kn = k[i] * rk * kw[d0 + i];
        float qo = __shfl_xor(qn, 2);
        float ko = __shfl_xor(kn, 2);
        qs[r][d0 + i] = qn * cs[i] + sgn * qo * sn[i];
        ks[r][d0 + i] = kn * cs[i] + sgn * ko * sn[i];
        vs[r][d0 + i] = v[i];
    }
    __syncthreads();

    float sc[4] = {0.f, 0.f, 0.f, 0.f};
    for (int d = 0; d < 64; d++) {
        const float qd = qs[r][d];
        sc[0] += qd * ks[qp     ][d];
        sc[1] += qd * ks[qp +  4][d];
        sc[2] += qd * ks[qp +  8][d];
        sc[3] += qd * ks[qp + 12][d];
    }
    #pragma unroll
    for (int cc = 0; cc < 4; cc++) {
        const int c = qp + cc * 4;
        sc[cc] = (c <= r) ? sc[cc] * 0.125f : -3.0e38f;
    }
    float mx = fmaxf(fmaxf(sc[0], sc[1]), fmaxf(sc[2], sc[3]));
    mx = fmaxf(mx, __shfl_xor(mx, 1));
    mx = fmaxf(mx, __shfl_xor(mx, 2));
    float e[4], sum = 0.f;
    #pragma unroll
    for (int cc = 0; cc < 4; cc++) { e[cc] = __expf(sc[cc] - mx); sum += e[cc]; }
    sum += __shfl_xor(sum, 1); sum += __shfl_xor(sum, 2);
    const float inv = 1.f / sum;
    #pragma unroll
    for (int cc = 0; cc < 4; cc++) ps[r][qp + cc * 4] = e[cc] * inv;
    __syncthreads();

    float o[16];
    #pragma unroll
    for (int i = 0; i < 16; i++) o[i] = 0.f;
    #pragma unroll
    for (int c = 0; c < 16; c++) {
        const float p = ps[r][c];
        #pragma unroll
        for (int i = 0; i < 16; i++) o[i] += p * vs[c][d0 + i];
    }

    __attribute__((aligned(16))) unsigned short ob[16];
    #pragma unroll
    for (int i = 0; i < 16; i++) ob[i] = f2b(o[i]);
    unsigned short* optr = out + (((size_t)(b * L_SEQ + pos0 + r) * NH + h) * HD) + d0;
    *(uint4*)optr       = *(uint4*)&ob[0];
    *((uint4*)optr + 1) = *(uint4*)&ob[8];
}

// ---------------------------------------------------------------------------
extern "C" void kernel_launch(void* const* d_in, const int* in_sizes, int n_in,
                              void* d_out, int out_size, void* d_ws, size_t ws_size,
                              hipStream_t stream) {
    const float* hid  = (const float*)d_in[0];
    const float* cosb = (const float*)d_in[2];
    const float* sinb = (const float*)d_in[3];
    const float* Wqkv = (const float*)d_in[4];
    const float* Wo   = (const float*)d_in[5];
    const float* qw   = (const float*)d_in[6];
    const float* kw   = (const float*)d_in[7];
    float* outp = (float*)d_out;

    char* ws = (char*)d_ws;
    unsigned short* Hb    = (unsigned short*)ws; ws += (size_t)M_ROWS * HID * 2;
    unsigned short* WqkvT = (unsigned short*)ws; ws += (size_t)QKV_N * HID * 2;
    unsigned short* WoT   = (unsigned short*)ws; ws += (size_t)HID * O_N * 2;
    unsigned short* qkvb  = (unsigned short*)ws; ws += (size_t)M_ROWS * QKV_N * 2;
    unsigned short* attnb = (unsigned short*)ws;

    {
        int n8 = (M_ROWS * HID) / 8;
        cvt_f32_bf16<<<(n8 + 255) / 256, 256, 0, stream>>>(hid, Hb, n8);
    }
    transpose_both<<<dim3(6144 + 4096), 256, 0, stream>>>(Wqkv, WqkvT, Wo, WoT);

    // GEMM1 (round-6 measured best, unchanged): qkv = H @ Wqkv
    gemm_sb<128, 192, 64, 3, 2, 4, true, unsigned short>
        <<<dim3((M_ROWS / 128) * (QKV_N / 192)), 512, 0, stream>>>
        (Hb, WqkvT, qkvb, M_ROWS, QKV_N, HID);

    // fused rmsnorm + rope + block-diag attention (bf16 in/out)
    attn_fused<<<dim3(B_SZ * (L_SEQ / 16) * NH), 64, 0, stream>>>(qkvb, cosb, sinb, qw, kw, attnb);

    // GEMM2 (NEW: m201-style 8-phase, 256^2 tile, grid 256 = 1/CU)
    gemm2_8p<<<dim3((M_ROWS / 256) * (HID / 256)), 512, 0, stream>>>
        (attnb, WoT, outp);
}